// Round 1
// baseline (308.100 us; speedup 1.0000x reference)
//
#include <hip/hip_runtime.h>
#include <stdint.h>

typedef unsigned short u16;
using f32x4 = __attribute__((ext_vector_type(4))) float;
using s16x8 = __attribute__((ext_vector_type(8))) short;
using s16x4 = __attribute__((ext_vector_type(4))) short;

__device__ __forceinline__ float bf2f(u16 u) {
  union { uint32_t u; float f; } v; v.u = ((uint32_t)u) << 16; return v.f;
}
__device__ __forceinline__ u16 f2bf(float f) {
  union { float f; uint32_t u; } v; v.f = f;
  uint32_t u = v.u;
  return (u16)((u + 0x7fffu + ((u >> 16) & 1u)) >> 16);
}

__device__ __forceinline__ void gload_lds16(const void* g, void* l) {
  __builtin_amdgcn_global_load_lds(
      (const __attribute__((address_space(1))) void*)g,
      (__attribute__((address_space(3))) void*)l, 16, 0, 0);
}

// ---------------- cast f32 -> bf16 (vectorized, grid-stride) ----------------
__global__ __launch_bounds__(256) void cast_bf16_kernel(
    const float* __restrict__ in, u16* __restrict__ out, int n8) {
  int idx = blockIdx.x * blockDim.x + threadIdx.x;
  int stride = gridDim.x * blockDim.x;
  for (int i = idx; i < n8; i += stride) {
    const float4* p = (const float4*)(in + (size_t)i * 8);
    float4 a = p[0], b = p[1];
    s16x8 o;
    o[0] = (short)f2bf(a.x); o[1] = (short)f2bf(a.y);
    o[2] = (short)f2bf(a.z); o[3] = (short)f2bf(a.w);
    o[4] = (short)f2bf(b.x); o[5] = (short)f2bf(b.y);
    o[6] = (short)f2bf(b.z); o[7] = (short)f2bf(b.w);
    *(s16x8*)(out + (size_t)i * 8) = o;
  }
}

// ------------- transpose-cast: W[K][N] f32 -> Wt[N][K] bf16 -----------------
__global__ __launch_bounds__(256) void tcast_kernel(
    const float* __restrict__ W, u16* __restrict__ Wt, int Kd, int Nd) {
  __shared__ u16 tile[32][33];
  int nbx = Nd / 32;
  int bx = blockIdx.x % nbx;
  int by = blockIdx.x / nbx;
  int tr = threadIdx.x >> 5;
  int tc = threadIdx.x & 31;
#pragma unroll
  for (int i = 0; i < 4; ++i)
    tile[tr + i * 8][tc] = f2bf(W[(size_t)(by * 32 + tr + i * 8) * Nd + bx * 32 + tc]);
  __syncthreads();
#pragma unroll
  for (int i = 0; i < 4; ++i)
    Wt[(size_t)(bx * 32 + tr + i * 8) * Kd + by * 32 + tc] = tile[tc][tr + i * 8];
}

// ---------------- row sums of exp-scores -> reciprocal ----------------------
__global__ __launch_bounds__(256) void rowsum_inv_kernel(
    const u16* __restrict__ S, float* __restrict__ invsum, int Ncols) {
  int row = blockIdx.x;
  const s16x8* p = (const s16x8*)(S + (size_t)row * Ncols);
  int n8 = Ncols >> 3;
  float s = 0.f;
  for (int i = threadIdx.x; i < n8; i += 256) {
    s16x8 v = p[i];
#pragma unroll
    for (int j = 0; j < 8; ++j) s += bf2f((u16)v[j]);
  }
#pragma unroll
  for (int off = 32; off > 0; off >>= 1) s += __shfl_down(s, off, 64);
  __shared__ float red[4];
  int lane = threadIdx.x & 63, wave = threadIdx.x >> 6;
  if (lane == 0) red[wave] = s;
  __syncthreads();
  if (threadIdx.x == 0) invsum[row] = 1.f / (red[0] + red[1] + red[2] + red[3]);
}

// ---------------- NT GEMM: C[M][N] = A[M][K] * Bt[N][K]^T -------------------
// 128x128 tile, BK=64, 4 waves (2x2), each wave 64x64 via 4x4 16x16x32 MFMA.
// EPI: 0 = bf16 store (+bias aux1), 1 = transposed bf16 store (+bias aux1),
//      2 = exp(acc/32) bf16 store, 3 = f32 store: aux1(x) + acc*aux2(invsum).
template <int EPI>
__global__ __launch_bounds__(256) void gemm_nt(
    const u16* __restrict__ A, const u16* __restrict__ Bt,
    void* __restrict__ Cout, int M, int N, int K,
    const float* __restrict__ aux1, const float* __restrict__ aux2) {
  constexpr int BK = 64;
  __shared__ u16 As[128 * BK];
  __shared__ u16 Bs[128 * BK];

  int nwg = gridDim.x;
  int bid = blockIdx.x;
  int swz = ((nwg & 7) == 0) ? ((bid & 7) * (nwg >> 3) + (bid >> 3)) : bid;
  int nbm = M >> 7;
  int bm = swz % nbm;
  int bn = swz / nbm;

  int tid = threadIdx.x;
  int lane = tid & 63;
  int wave = tid >> 6;
  int wm = (wave >> 1) << 6;
  int wn = (wave & 1) << 6;
  size_t m0 = (size_t)bm << 7;
  size_t n0 = (size_t)bn << 7;

  int srow = tid >> 3;         // 0..31 (row within 32-row staging chunk)
  int scol = (tid & 7) << 3;   // 0,8,...,56

  f32x4 acc[4][4] = {};

  const u16* Ag = A + (m0 + srow) * K + scol;
  const u16* Bg = Bt + (n0 + srow) * K + scol;
  u16* Asw = &As[wave * 512];  // wave-uniform LDS base (elems)
  u16* Bsw = &Bs[wave * 512];

  int laneh = lane & 15;
  int lanev = lane >> 4;

  for (int k0 = 0; k0 < K; k0 += BK) {
#pragma unroll
    for (int i = 0; i < 4; ++i) {
      gload_lds16(Ag + (size_t)i * 32 * K + k0, Asw + i * 2048);
      gload_lds16(Bg + (size_t)i * 32 * K + k0, Bsw + i * 2048);
    }
    __syncthreads();
#pragma unroll
    for (int kk = 0; kk < 2; ++kk) {
      s16x8 af[4], bfr[4];
#pragma unroll
      for (int i = 0; i < 4; ++i) {
        af[i]  = *(const s16x8*)&As[(wm + i * 16 + laneh) * BK + kk * 32 + lanev * 8];
        bfr[i] = *(const s16x8*)&Bs[(wn + i * 16 + laneh) * BK + kk * 32 + lanev * 8];
      }
#pragma unroll
      for (int mi = 0; mi < 4; ++mi)
#pragma unroll
        for (int ni = 0; ni < 4; ++ni)
          acc[mi][ni] = __builtin_amdgcn_mfma_f32_16x16x32_bf16(
              af[mi], bfr[ni], acc[mi][ni], 0, 0, 0);
    }
    __syncthreads();
  }

  // C/D layout: col = lane&15, row = (lane>>4)*4 + reg   [guide §3, m89/m91]
  int crow = (int)m0 + wm + (lanev << 2);
  int ccol = (int)n0 + wn + laneh;

  if constexpr (EPI == 0) {
    u16* C = (u16*)Cout;
#pragma unroll
    for (int mi = 0; mi < 4; ++mi)
#pragma unroll
      for (int r = 0; r < 4; ++r) {
        size_t row = (size_t)(crow + mi * 16 + r);
#pragma unroll
        for (int ni = 0; ni < 4; ++ni)
          C[row * N + ccol + ni * 16] = f2bf(acc[mi][ni][r] + aux1[ccol + ni * 16]);
      }
  } else if constexpr (EPI == 1) {
    u16* C = (u16*)Cout;  // [N][M]
#pragma unroll
    for (int ni = 0; ni < 4; ++ni) {
      float b = aux1[ccol + ni * 16];
#pragma unroll
      for (int mi = 0; mi < 4; ++mi) {
        s16x4 v;
#pragma unroll
        for (int r = 0; r < 4; ++r) v[r] = (short)f2bf(acc[mi][ni][r] + b);
        *(s16x4*)&C[(size_t)(ccol + ni * 16) * M + crow + mi * 16] = v;
      }
    }
  } else if constexpr (EPI == 2) {
    u16* C = (u16*)Cout;
#pragma unroll
    for (int mi = 0; mi < 4; ++mi)
#pragma unroll
      for (int r = 0; r < 4; ++r) {
        size_t row = (size_t)(crow + mi * 16 + r);
#pragma unroll
        for (int ni = 0; ni < 4; ++ni)
          C[row * N + ccol + ni * 16] = f2bf(__expf(acc[mi][ni][r] * 0.03125f));
      }
  } else {
    float* C = (float*)Cout;
#pragma unroll
    for (int mi = 0; mi < 4; ++mi)
#pragma unroll
      for (int r = 0; r < 4; ++r) {
        size_t row = (size_t)(crow + mi * 16 + r);
        float inv = aux2[row];
#pragma unroll
        for (int ni = 0; ni < 4; ++ni)
          C[row * N + ccol + ni * 16] =
              aux1[row * N + ccol + ni * 16] + acc[mi][ni][r] * inv;
      }
  }
}

extern "C" void kernel_launch(void* const* d_in, const int* in_sizes, int n_in,
                              void* d_out, int out_size, void* d_ws, size_t ws_size,
                              hipStream_t stream) {
  const float* x  = (const float*)d_in[0];
  const float* mb = (const float*)d_in[1];
  const float* Wq = (const float*)d_in[2];
  const float* bq = (const float*)d_in[3];
  const float* Wk = (const float*)d_in[4];
  const float* bk = (const float*)d_in[5];
  const float* Wv = (const float*)d_in[6];
  const float* bv = (const float*)d_in[7];
  float* out = (float*)d_out;

  const int B = 8192, H = 1024, Mm = 4096;

  char* ws = (char*)d_ws;
  u16* xb  = (u16*)ws; ws += (size_t)B * H * 2;
  u16* mbb = (u16*)ws; ws += (size_t)Mm * H * 2;
  u16* Wqt = (u16*)ws; ws += (size_t)H * H * 2;
  u16* Wkt = (u16*)ws; ws += (size_t)H * H * 2;
  u16* Wvt = (u16*)ws; ws += (size_t)H * H * 2;
  u16* Q   = (u16*)ws; ws += (size_t)B * H * 2;
  u16* Kp  = (u16*)ws; ws += (size_t)Mm * H * 2;
  u16* Vt  = (u16*)ws; ws += (size_t)H * Mm * 2;
  u16* S   = (u16*)ws; ws += (size_t)B * Mm * 2;
  float* invs = (float*)ws;

  cast_bf16_kernel<<<2048, 256, 0, stream>>>(x, xb, B * H / 8);
  cast_bf16_kernel<<<1024, 256, 0, stream>>>(mb, mbb, Mm * H / 8);
  tcast_kernel<<<(H / 32) * (H / 32), 256, 0, stream>>>(Wq, Wqt, H, H);
  tcast_kernel<<<(H / 32) * (H / 32), 256, 0, stream>>>(Wk, Wkt, H, H);
  tcast_kernel<<<(H / 32) * (H / 32), 256, 0, stream>>>(Wv, Wvt, H, H);

  gemm_nt<0><<<(B / 128) * (H / 128), 256, 0, stream>>>(xb, Wqt, Q, B, H, H, bq, nullptr);
  gemm_nt<0><<<(Mm / 128) * (H / 128), 256, 0, stream>>>(mbb, Wkt, Kp, Mm, H, H, bk, nullptr);
  gemm_nt<1><<<(Mm / 128) * (H / 128), 256, 0, stream>>>(mbb, Wvt, Vt, Mm, H, H, bv, nullptr);

  gemm_nt<2><<<(B / 128) * (Mm / 128), 256, 0, stream>>>(Q, Kp, S, B, Mm, H, nullptr, nullptr);
  rowsum_inv_kernel<<<B, 256, 0, stream>>>(S, invs, Mm);
  gemm_nt<3><<<(B / 128) * (H / 128), 256, 0, stream>>>(S, Vt, out, B, H, Mm, x, invs);
}

// Round 2
// 281.666 us; speedup vs baseline: 1.0938x; 1.0938x over previous
//
#include <hip/hip_runtime.h>
#include <stdint.h>

typedef unsigned short u16;
using f32x4 = __attribute__((ext_vector_type(4))) float;
using s16x8 = __attribute__((ext_vector_type(8))) short;
using s16x4 = __attribute__((ext_vector_type(4))) short;

__device__ __forceinline__ float bf2f(u16 u) {
  union { uint32_t u; float f; } v; v.u = ((uint32_t)u) << 16; return v.f;
}
__device__ __forceinline__ u16 f2bf(float f) {
  union { float f; uint32_t u; } v; v.f = f;
  uint32_t u = v.u;
  return (u16)((u + 0x7fffu + ((u >> 16) & 1u)) >> 16);
}

__device__ __forceinline__ void gload_lds16(const void* g, void* l) {
  __builtin_amdgcn_global_load_lds(
      (const __attribute__((address_space(1))) void*)g,
      (__attribute__((address_space(3))) void*)l, 16, 0, 0);
}

// ---------------- cast f32 -> bf16 (vectorized, grid-stride) ----------------
__global__ __launch_bounds__(256) void cast_bf16_kernel(
    const float* __restrict__ in, u16* __restrict__ out, int n8) {
  int idx = blockIdx.x * blockDim.x + threadIdx.x;
  int stride = gridDim.x * blockDim.x;
  for (int i = idx; i < n8; i += stride) {
    const float4* p = (const float4*)(in + (size_t)i * 8);
    float4 a = p[0], b = p[1];
    s16x8 o;
    o[0] = (short)f2bf(a.x); o[1] = (short)f2bf(a.y);
    o[2] = (short)f2bf(a.z); o[3] = (short)f2bf(a.w);
    o[4] = (short)f2bf(b.x); o[5] = (short)f2bf(b.y);
    o[6] = (short)f2bf(b.z); o[7] = (short)f2bf(b.w);
    *(s16x8*)(out + (size_t)i * 8) = o;
  }
}

// ------------- transpose-cast: W[K][N] f32 -> Wt[N][K] bf16 -----------------
__global__ __launch_bounds__(256) void tcast_kernel(
    const float* __restrict__ W, u16* __restrict__ Wt, int Kd, int Nd) {
  __shared__ u16 tile[32][33];
  int nbx = Nd / 32;
  int bx = blockIdx.x % nbx;
  int by = blockIdx.x / nbx;
  int tr = threadIdx.x >> 5;
  int tc = threadIdx.x & 31;
#pragma unroll
  for (int i = 0; i < 4; ++i)
    tile[tr + i * 8][tc] = f2bf(W[(size_t)(by * 32 + tr + i * 8) * Nd + bx * 32 + tc]);
  __syncthreads();
#pragma unroll
  for (int i = 0; i < 4; ++i)
    Wt[(size_t)(bx * 32 + tr + i * 8) * Kd + by * 32 + tc] = tile[tc][tr + i * 8];
}

// ---------------- row sums of exp-scores -> reciprocal ----------------------
__global__ __launch_bounds__(256) void rowsum_inv_kernel(
    const u16* __restrict__ S, float* __restrict__ invsum, int Ncols) {
  int row = blockIdx.x;
  const s16x8* p = (const s16x8*)(S + (size_t)row * Ncols);
  int n8 = Ncols >> 3;
  float s = 0.f;
  for (int i = threadIdx.x; i < n8; i += 256) {
    s16x8 v = p[i];
#pragma unroll
    for (int j = 0; j < 8; ++j) s += bf2f((u16)v[j]);
  }
#pragma unroll
  for (int off = 32; off > 0; off >>= 1) s += __shfl_down(s, off, 64);
  __shared__ float red[4];
  int lane = threadIdx.x & 63, wave = threadIdx.x >> 6;
  if (lane == 0) red[wave] = s;
  __syncthreads();
  if (threadIdx.x == 0) invsum[row] = 1.f / (red[0] + red[1] + red[2] + red[3]);
}

// ======================= 8-phase 256x256 QK^T kernel ========================
// C[M][N] = exp((A[M][K] @ Bt[N][K]^T) / 32) in bf16.
// 8 waves (2Mx4N), BK=64, K-half staging, swizzled LDS, counted vmcnt gates.

#define GATE8 asm volatile("s_waitcnt vmcnt(8)" ::: "memory")
#define GATE4 asm volatile("s_waitcnt vmcnt(4)" ::: "memory")
#define GATE0 asm volatile("s_waitcnt vmcnt(0)" ::: "memory")
#define NOGATE (void)0
#define NOSTG (void)0

#define STG_A(buf, h, kt) do { \
    const u16* s_ = Asrc + (size_t)(kt) * 64 + (h) * 32; \
    gload_lds16(s_, &As[buf][h][wave * 512]); \
    gload_lds16(s_ + srow128, &As[buf][h][wave * 512 + 4096]); \
  } while (0)

#define STG_B(buf, h, kt) do { \
    const u16* s_ = Bsrc + (size_t)(kt) * 64 + (h) * 32; \
    gload_lds16(s_, &Bs[buf][h][wave * 512]); \
    gload_lds16(s_ + srow128, &Bs[buf][h][wave * 512 + 4096]); \
  } while (0)

#define DS_FRAGS(buf, kk, mh) do { \
    const u16* ab_ = &As[buf][kk][(wm + (mh) * 64 + laneh) * 32 + aswz]; \
    af[0] = *(const s16x8*)(ab_); \
    af[1] = *(const s16x8*)(ab_ + 512); \
    af[2] = *(const s16x8*)(ab_ + 1024); \
    af[3] = *(const s16x8*)(ab_ + 1536); \
    if ((mh) == 0) { \
      const u16* bb_ = &Bs[buf][kk][(wn + laneh) * 32 + aswz]; \
      bf[0] = *(const s16x8*)(bb_); \
      bf[1] = *(const s16x8*)(bb_ + 512); \
      bf[2] = *(const s16x8*)(bb_ + 1024); \
      bf[3] = *(const s16x8*)(bb_ + 1536); \
    } \
  } while (0)

#define PHASE(buf, kk, mh, STAGE, GATE) do { \
    DS_FRAGS(buf, kk, mh); \
    STAGE; \
    __builtin_amdgcn_s_barrier(); \
    asm volatile("s_waitcnt lgkmcnt(0)" ::: "memory"); \
    __builtin_amdgcn_sched_barrier(0); \
    __builtin_amdgcn_s_setprio(1); \
    _Pragma("unroll") \
    for (int i2 = 0; i2 < 4; ++i2) \
      _Pragma("unroll") \
      for (int j2 = 0; j2 < 4; ++j2) \
        acc[(mh) * 4 + i2][j2] = __builtin_amdgcn_mfma_f32_16x16x32_bf16( \
            af[i2], bf[j2], acc[(mh) * 4 + i2][j2], 0, 0, 0); \
    __builtin_amdgcn_s_setprio(0); \
    GATE; \
    __builtin_amdgcn_s_barrier(); \
  } while (0)

__global__ __launch_bounds__(512, 2) void gemm_qkt_exp(
    const u16* __restrict__ A, const u16* __restrict__ Bt, u16* __restrict__ C,
    int M, int N, int Kd) {
  // LDS: [buf][khalf][256 rows][32 elems], swizzled 16B slots within 64B rows
  __shared__ u16 As[2][2][256 * 32];
  __shared__ u16 Bs[2][2][256 * 32];

  int nwg = gridDim.x;
  int bid = blockIdx.x;
  int swz = ((nwg & 7) == 0) ? ((bid & 7) * (nwg >> 3) + (bid >> 3)) : bid;
  int nbm = M >> 8;
  int bm = swz % nbm;
  int bn = swz / nbm;
  size_t m0 = (size_t)bm << 8;
  size_t n0 = (size_t)bn << 8;

  int tid = threadIdx.x;
  int lane = tid & 63;
  int wave = tid >> 6;
  int wm = (wave >> 2) * 128;  // 0 or 128
  int wn = (wave & 3) * 64;    // 0..192
  int laneh = lane & 15;
  int lanev = lane >> 4;
  // read-side swizzle: physical slot = logical slot (lanev) ^ ((row>>1)&3)
  int aswz = ((lanev ^ ((laneh >> 1) & 3)) << 3);

  // staging source: thread writes physical 16B slot tid within a region;
  // logical k-slot for that physical slot:
  int prow = tid >> 2;
  int lslot = (tid & 3) ^ ((tid >> 3) & 3);
  const u16* Asrc = A + (m0 + prow) * Kd + lslot * 8;
  const u16* Bsrc = Bt + (n0 + prow) * Kd + lslot * 8;
  size_t srow128 = (size_t)128 * Kd;

  f32x4 acc[8][4] = {};
  s16x8 af[4], bf[4];

  // prologue: T0 (both k-halves) + T1 k-half0
  STG_A(0, 0, 0); STG_B(0, 0, 0);
  STG_A(0, 1, 0); STG_B(0, 1, 0);
  STG_A(1, 0, 1); STG_B(1, 0, 1);
  GATE4;
  __builtin_amdgcn_s_barrier();

  int NI = Kd >> 7;  // iterations over tile pairs
  for (int it = 0; it < NI - 1; ++it) {
    int t = 2 * it;
    PHASE(0, 0, 0, STG_A(1, 1, t + 1), NOGATE);
    PHASE(0, 0, 1, STG_B(1, 1, t + 1), GATE8);
    PHASE(0, 1, 0, STG_A(0, 0, t + 2), NOGATE);
    PHASE(0, 1, 1, STG_B(0, 0, t + 2), GATE8);
    PHASE(1, 0, 0, STG_A(0, 1, t + 2), NOGATE);
    PHASE(1, 0, 1, STG_B(0, 1, t + 2), GATE8);
    PHASE(1, 1, 0, STG_A(1, 0, t + 3), NOGATE);
    PHASE(1, 1, 1, STG_B(1, 0, t + 3), GATE8);
  }
  {  // final iteration: drain
    int t = 2 * (NI - 1);
    PHASE(0, 0, 0, STG_A(1, 1, t + 1), NOGATE);
    PHASE(0, 0, 1, STG_B(1, 1, t + 1), GATE8);
    PHASE(0, 1, 0, NOSTG, NOGATE);
    PHASE(0, 1, 1, NOSTG, GATE4);
    PHASE(1, 0, 0, NOSTG, NOGATE);
    PHASE(1, 0, 1, NOSTG, GATE0);
    PHASE(1, 1, 0, NOSTG, NOGATE);
    PHASE(1, 1, 1, NOSTG, NOGATE);
  }

  // epilogue: C = exp(acc/32) bf16.  C/D frag: col=laneh, row=lanev*4+r
  int crow = (int)m0 + wm + (lanev << 2);
  int ccol = (int)n0 + wn + laneh;
#pragma unroll
  for (int a = 0; a < 8; ++a) {
    int rowoff = ((a >> 2) * 64) + ((a & 3) * 16);
#pragma unroll
    for (int r = 0; r < 4; ++r) {
      size_t rbase = (size_t)(crow + rowoff + r) * N + ccol;
#pragma unroll
      for (int j = 0; j < 4; ++j)
        C[rbase + j * 16] = f2bf(__expf(acc[a][j][r] * 0.03125f));
    }
  }
}

// ---------------- NT GEMM: C[M][N] = A[M][K] * Bt[N][K]^T (128^2) -----------
// EPI: 0 = bf16 store (+bias aux1), 1 = transposed bf16 store (+bias aux1),
//      3 = f32 store: aux1(x) + acc*aux2(invsum).
template <int EPI>
__global__ __launch_bounds__(256) void gemm_nt(
    const u16* __restrict__ A, const u16* __restrict__ Bt,
    void* __restrict__ Cout, int M, int N, int K,
    const float* __restrict__ aux1, const float* __restrict__ aux2) {
  constexpr int BK = 64;
  __shared__ u16 As[128 * BK];
  __shared__ u16 Bs[128 * BK];

  int nwg = gridDim.x;
  int bid = blockIdx.x;
  int swz = ((nwg & 7) == 0) ? ((bid & 7) * (nwg >> 3) + (bid >> 3)) : bid;
  int nbm = M >> 7;
  int bm = swz % nbm;
  int bn = swz / nbm;

  int tid = threadIdx.x;
  int lane = tid & 63;
  int wave = tid >> 6;
  int wm = (wave >> 1) << 6;
  int wn = (wave & 1) << 6;
  size_t m0 = (size_t)bm << 7;
  size_t n0 = (size_t)bn << 7;

  int srow = tid >> 3;
  int scol = (tid & 7) << 3;

  f32x4 acc[4][4] = {};

  const u16* Ag = A + (m0 + srow) * K + scol;
  const u16* Bg = Bt + (n0 + srow) * K + scol;
  u16* Asw = &As[wave * 512];
  u16* Bsw = &Bs[wave * 512];

  int laneh = lane & 15;
  int lanev = lane >> 4;

  for (int k0 = 0; k0 < K; k0 += BK) {
#pragma unroll
    for (int i = 0; i < 4; ++i) {
      gload_lds16(Ag + (size_t)i * 32 * K + k0, Asw + i * 2048);
      gload_lds16(Bg + (size_t)i * 32 * K + k0, Bsw + i * 2048);
    }
    __syncthreads();
#pragma unroll
    for (int kk = 0; kk < 2; ++kk) {
      s16x8 af[4], bfr[4];
#pragma unroll
      for (int i = 0; i < 4; ++i) {
        af[i]  = *(const s16x8*)&As[(wm + i * 16 + laneh) * BK + kk * 32 + lanev * 8];
        bfr[i] = *(const s16x8*)&Bs[(wn + i * 16 + laneh) * BK + kk * 32 + lanev * 8];
      }
#pragma unroll
      for (int mi = 0; mi < 4; ++mi)
#pragma unroll
        for (int ni = 0; ni < 4; ++ni)
          acc[mi][ni] = __builtin_amdgcn_mfma_f32_16x16x32_bf16(
              af[mi], bfr[ni], acc[mi][ni], 0, 0, 0);
    }
    __syncthreads();
  }

  int crow = (int)m0 + wm + (lanev << 2);
  int ccol = (int)n0 + wn + laneh;

  if constexpr (EPI == 0) {
    u16* C = (u16*)Cout;
#pragma unroll
    for (int mi = 0; mi < 4; ++mi)
#pragma unroll
      for (int r = 0; r < 4; ++r) {
        size_t row = (size_t)(crow + mi * 16 + r);
#pragma unroll
        for (int ni = 0; ni < 4; ++ni)
          C[row * N + ccol + ni * 16] = f2bf(acc[mi][ni][r] + aux1[ccol + ni * 16]);
      }
  } else if constexpr (EPI == 1) {
    u16* C = (u16*)Cout;  // [N][M]
#pragma unroll
    for (int ni = 0; ni < 4; ++ni) {
      float b = aux1[ccol + ni * 16];
#pragma unroll
      for (int mi = 0; mi < 4; ++mi) {
        s16x4 v;
#pragma unroll
        for (int r = 0; r < 4; ++r) v[r] = (short)f2bf(acc[mi][ni][r] + b);
        *(s16x4*)&C[(size_t)(ccol + ni * 16) * M + crow + mi * 16] = v;
      }
    }
  } else {
    float* C = (float*)Cout;
#pragma unroll
    for (int mi = 0; mi < 4; ++mi)
#pragma unroll
      for (int r = 0; r < 4; ++r) {
        size_t row = (size_t)(crow + mi * 16 + r);
        float inv = aux2[row];
#pragma unroll
        for (int ni = 0; ni < 4; ++ni)
          C[row * N + ccol + ni * 16] =
              aux1[row * N + ccol + ni * 16] + acc[mi][ni][r] * inv;
      }
  }
}

extern "C" void kernel_launch(void* const* d_in, const int* in_sizes, int n_in,
                              void* d_out, int out_size, void* d_ws, size_t ws_size,
                              hipStream_t stream) {
  const float* x  = (const float*)d_in[0];
  const float* mb = (const float*)d_in[1];
  const float* Wq = (const float*)d_in[2];
  const float* bq = (const float*)d_in[3];
  const float* Wk = (const float*)d_in[4];
  const float* bk = (const float*)d_in[5];
  const float* Wv = (const float*)d_in[6];
  const float* bv = (const float*)d_in[7];
  float* out = (float*)d_out;

  const int B = 8192, H = 1024, Mm = 4096;

  char* ws = (char*)d_ws;
  u16* xb  = (u16*)ws; ws += (size_t)B * H * 2;
  u16* mbb = (u16*)ws; ws += (size_t)Mm * H * 2;
  u16* Wqt = (u16*)ws; ws += (size_t)H * H * 2;
  u16* Wkt = (u16*)ws; ws += (size_t)H * H * 2;
  u16* Wvt = (u16*)ws; ws += (size_t)H * H * 2;
  u16* Q   = (u16*)ws; ws += (size_t)B * H * 2;
  u16* Kp  = (u16*)ws; ws += (size_t)Mm * H * 2;
  u16* Vt  = (u16*)ws; ws += (size_t)H * Mm * 2;
  u16* S   = (u16*)ws; ws += (size_t)B * Mm * 2;
  float* invs = (float*)ws;

  cast_bf16_kernel<<<2048, 256, 0, stream>>>(x, xb, B * H / 8);
  cast_bf16_kernel<<<1024, 256, 0, stream>>>(mb, mbb, Mm * H / 8);
  tcast_kernel<<<(H / 32) * (H / 32), 256, 0, stream>>>(Wq, Wqt, H, H);
  tcast_kernel<<<(H / 32) * (H / 32), 256, 0, stream>>>(Wk, Wkt, H, H);
  tcast_kernel<<<(H / 32) * (H / 32), 256, 0, stream>>>(Wv, Wvt, H, H);

  gemm_nt<0><<<(B / 128) * (H / 128), 256, 0, stream>>>(xb, Wqt, Q, B, H, H, bq, nullptr);
  gemm_nt<0><<<(Mm / 128) * (H / 128), 256, 0, stream>>>(mbb, Wkt, Kp, Mm, H, H, bk, nullptr);
  gemm_nt<1><<<(Mm / 128) * (H / 128), 256, 0, stream>>>(mbb, Wvt, Vt, Mm, H, H, bv, nullptr);

  gemm_qkt_exp<<<(B / 256) * (Mm / 256), 512, 0, stream>>>(Q, Kp, S, B, Mm, H);

  rowsum_inv_kernel<<<B, 256, 0, stream>>>(S, invs, Mm);
  gemm_nt<3><<<(B / 128) * (H / 128), 256, 0, stream>>>(S, Vt, out, B, H, Mm, x, invs);
}

// Round 3
// 267.918 us; speedup vs baseline: 1.1500x; 1.0513x over previous
//
#include <hip/hip_runtime.h>
#include <stdint.h>

typedef unsigned short u16;
using f32x4 = __attribute__((ext_vector_type(4))) float;
using s16x8 = __attribute__((ext_vector_type(8))) short;
using s16x4 = __attribute__((ext_vector_type(4))) short;

__device__ __forceinline__ float bf2f(u16 u) {
  union { uint32_t u; float f; } v; v.u = ((uint32_t)u) << 16; return v.f;
}
__device__ __forceinline__ u16 f2bf(float f) {
  union { float f; uint32_t u; } v; v.f = f;
  uint32_t u = v.u;
  return (u16)((u + 0x7fffu + ((u >> 16) & 1u)) >> 16);
}

__device__ __forceinline__ void gload_lds16(const void* g, void* l) {
  __builtin_amdgcn_global_load_lds(
      (const __attribute__((address_space(1))) void*)g,
      (__attribute__((address_space(3))) void*)l, 16, 0, 0);
}

// ---------------- cast f32 -> bf16 (vectorized, grid-stride) ----------------
__global__ __launch_bounds__(256) void cast_bf16_kernel(
    const float* __restrict__ in, u16* __restrict__ out, int n8) {
  int idx = blockIdx.x * blockDim.x + threadIdx.x;
  int stride = gridDim.x * blockDim.x;
  for (int i = idx; i < n8; i += stride) {
    const float4* p = (const float4*)(in + (size_t)i * 8);
    float4 a = p[0], b = p[1];
    s16x8 o;
    o[0] = (short)f2bf(a.x); o[1] = (short)f2bf(a.y);
    o[2] = (short)f2bf(a.z); o[3] = (short)f2bf(a.w);
    o[4] = (short)f2bf(b.x); o[5] = (short)f2bf(b.y);
    o[6] = (short)f2bf(b.z); o[7] = (short)f2bf(b.w);
    *(s16x8*)(out + (size_t)i * 8) = o;
  }
}

// ------------- transpose-cast: W[K][N] f32 -> Wt[N][K] bf16 -----------------
__global__ __launch_bounds__(256) void tcast_kernel(
    const float* __restrict__ W, u16* __restrict__ Wt, int Kd, int Nd) {
  __shared__ u16 tile[32][33];
  int nbx = Nd / 32;
  int bx = blockIdx.x % nbx;
  int by = blockIdx.x / nbx;
  int tr = threadIdx.x >> 5;
  int tc = threadIdx.x & 31;
#pragma unroll
  for (int i = 0; i < 4; ++i)
    tile[tr + i * 8][tc] = f2bf(W[(size_t)(by * 32 + tr + i * 8) * Nd + bx * 32 + tc]);
  __syncthreads();
#pragma unroll
  for (int i = 0; i < 4; ++i)
    Wt[(size_t)(bx * 32 + tr + i * 8) * Kd + by * 32 + tc] = tile[tc][tr + i * 8];
}

// ---------------- row sums of exp-scores -> reciprocal ----------------------
__global__ __launch_bounds__(256) void rowsum_inv_kernel(
    const u16* __restrict__ S, float* __restrict__ invsum, int Ncols) {
  int row = blockIdx.x;
  const s16x8* p = (const s16x8*)(S + (size_t)row * Ncols);
  int n8 = Ncols >> 3;
  float s = 0.f;
  for (int i = threadIdx.x; i < n8; i += 256) {
    s16x8 v = p[i];
#pragma unroll
    for (int j = 0; j < 8; ++j) s += bf2f((u16)v[j]);
  }
#pragma unroll
  for (int off = 32; off > 0; off >>= 1) s += __shfl_down(s, off, 64);
  __shared__ float red[4];
  int lane = threadIdx.x & 63, wave = threadIdx.x >> 6;
  if (lane == 0) red[wave] = s;
  __syncthreads();
  if (threadIdx.x == 0) invsum[row] = 1.f / (red[0] + red[1] + red[2] + red[3]);
}

// ============================ gate / stage macros ===========================
#define GATE8 asm volatile("s_waitcnt vmcnt(8)" ::: "memory")
#define GATE6 asm volatile("s_waitcnt vmcnt(6)" ::: "memory")
#define GATE4 asm volatile("s_waitcnt vmcnt(4)" ::: "memory")
#define GATE3 asm volatile("s_waitcnt vmcnt(3)" ::: "memory")
#define GATE0 asm volatile("s_waitcnt vmcnt(0)" ::: "memory")
#define NOGATE (void)0
#define NOSTG (void)0

// ======================= 8-phase 256x256 QK^T kernel ========================
// C[M][N] = exp((A[M][K] @ Bt[N][K]^T) / 32) in bf16.

#define STG_A(buf, h, kt) do { \
    const u16* s_ = Asrc + (size_t)(kt) * 64 + (h) * 32; \
    gload_lds16(s_, &As[buf][h][wave * 512]); \
    gload_lds16(s_ + srow128, &As[buf][h][wave * 512 + 4096]); \
  } while (0)

#define STG_B(buf, h, kt) do { \
    const u16* s_ = Bsrc + (size_t)(kt) * 64 + (h) * 32; \
    gload_lds16(s_, &Bs[buf][h][wave * 512]); \
    gload_lds16(s_ + srow128, &Bs[buf][h][wave * 512 + 4096]); \
  } while (0)

#define DS_FRAGS(buf, kk, mh) do { \
    const u16* ab_ = &As[buf][kk][(wm + (mh) * 64 + laneh) * 32 + aswz]; \
    af[0] = *(const s16x8*)(ab_); \
    af[1] = *(const s16x8*)(ab_ + 512); \
    af[2] = *(const s16x8*)(ab_ + 1024); \
    af[3] = *(const s16x8*)(ab_ + 1536); \
    if ((mh) == 0) { \
      const u16* bb_ = &Bs[buf][kk][(wn + laneh) * 32 + aswz]; \
      bf[0] = *(const s16x8*)(bb_); \
      bf[1] = *(const s16x8*)(bb_ + 512); \
      bf[2] = *(const s16x8*)(bb_ + 1024); \
      bf[3] = *(const s16x8*)(bb_ + 1536); \
    } \
  } while (0)

#define PHASE(buf, kk, mh, STAGE, GATE) do { \
    DS_FRAGS(buf, kk, mh); \
    STAGE; \
    __builtin_amdgcn_s_barrier(); \
    asm volatile("s_waitcnt lgkmcnt(0)" ::: "memory"); \
    __builtin_amdgcn_sched_barrier(0); \
    __builtin_amdgcn_s_setprio(1); \
    _Pragma("unroll") \
    for (int i2 = 0; i2 < 4; ++i2) \
      _Pragma("unroll") \
      for (int j2 = 0; j2 < 4; ++j2) \
        acc[(mh) * 4 + i2][j2] = __builtin_amdgcn_mfma_f32_16x16x32_bf16( \
            af[i2], bf[j2], acc[(mh) * 4 + i2][j2], 0, 0, 0); \
    __builtin_amdgcn_s_setprio(0); \
    GATE; \
    __builtin_amdgcn_s_barrier(); \
  } while (0)

__global__ __launch_bounds__(512, 2) void gemm_qkt_exp(
    const u16* __restrict__ A, const u16* __restrict__ Bt, u16* __restrict__ C,
    int M, int N, int Kd) {
  __shared__ u16 As[2][2][256 * 32];
  __shared__ u16 Bs[2][2][256 * 32];

  int nwg = gridDim.x;
  int bid = blockIdx.x;
  int swz = ((nwg & 7) == 0) ? ((bid & 7) * (nwg >> 3) + (bid >> 3)) : bid;
  int nbm = M >> 8;
  int bm = swz % nbm;
  int bn = swz / nbm;
  size_t m0 = (size_t)bm << 8;
  size_t n0 = (size_t)bn << 8;

  int tid = threadIdx.x;
  int lane = tid & 63;
  int wave = tid >> 6;
  int wm = (wave >> 2) * 128;
  int wn = (wave & 3) * 64;
  int laneh = lane & 15;
  int lanev = lane >> 4;
  int aswz = ((lanev ^ ((laneh >> 1) & 3)) << 3);

  int prow = tid >> 2;
  int lslot = (tid & 3) ^ ((tid >> 3) & 3);
  const u16* Asrc = A + (m0 + prow) * Kd + lslot * 8;
  const u16* Bsrc = Bt + (n0 + prow) * Kd + lslot * 8;
  size_t srow128 = (size_t)128 * Kd;

  f32x4 acc[8][4] = {};
  s16x8 af[4], bf[4];

  STG_A(0, 0, 0); STG_B(0, 0, 0);
  STG_A(0, 1, 0); STG_B(0, 1, 0);
  STG_A(1, 0, 1); STG_B(1, 0, 1);
  GATE4;
  __builtin_amdgcn_s_barrier();

  int NI = Kd >> 7;
  for (int it = 0; it < NI - 1; ++it) {
    int t = 2 * it;
    PHASE(0, 0, 0, STG_A(1, 1, t + 1), NOGATE);
    PHASE(0, 0, 1, STG_B(1, 1, t + 1), GATE8);
    PHASE(0, 1, 0, STG_A(0, 0, t + 2), NOGATE);
    PHASE(0, 1, 1, STG_B(0, 0, t + 2), GATE8);
    PHASE(1, 0, 0, STG_A(0, 1, t + 2), NOGATE);
    PHASE(1, 0, 1, STG_B(0, 1, t + 2), GATE8);
    PHASE(1, 1, 0, STG_A(1, 0, t + 3), NOGATE);
    PHASE(1, 1, 1, STG_B(1, 0, t + 3), GATE8);
  }
  {
    int t = 2 * (NI - 1);
    PHASE(0, 0, 0, STG_A(1, 1, t + 1), NOGATE);
    PHASE(0, 0, 1, STG_B(1, 1, t + 1), GATE8);
    PHASE(0, 1, 0, NOSTG, NOGATE);
    PHASE(0, 1, 1, NOSTG, GATE4);
    PHASE(1, 0, 0, NOSTG, NOGATE);
    PHASE(1, 0, 1, NOSTG, GATE0);
    PHASE(1, 1, 0, NOSTG, NOGATE);
    PHASE(1, 1, 1, NOSTG, NOGATE);
  }

  int crow = (int)m0 + wm + (lanev << 2);
  int ccol = (int)n0 + wn + laneh;
#pragma unroll
  for (int a = 0; a < 8; ++a) {
    int rowoff = ((a >> 2) * 64) + ((a & 3) * 16);
#pragma unroll
    for (int r = 0; r < 4; ++r) {
      size_t rbase = (size_t)(crow + rowoff + r) * N + ccol;
#pragma unroll
      for (int j = 0; j < 4; ++j)
        C[rbase + j * 16] = f2bf(__expf(acc[a][j][r] * 0.03125f));
    }
  }
}

// ====================== 4-phase 256x128 PV kernel ===========================
// C[M][N] f32 = xres + (A[M][K]bf16 @ Bt[N][K]^T) * invs[row]
// 8 waves (4Mx2N), per-wave 64x64, BK=64, vmcnt(6) gate per phase.

#define PSTG(buf, h, kt) do { \
    const u16* sa_ = Asrc + (size_t)(kt) * 64 + (h) * 32; \
    gload_lds16(sa_, &As[buf][h][wave * 512]); \
    gload_lds16(sa_ + srow128, &As[buf][h][wave * 512 + 4096]); \
    const u16* sb_ = Bsrc + (size_t)(kt) * 64 + (h) * 32; \
    gload_lds16(sb_, &Bs[buf][h][wave * 512]); \
  } while (0)

#define PPHASE(buf, kk, STAGE, GATE) do { \
    { const u16* ab_ = &As[buf][kk][(wm + laneh) * 32 + aswz]; \
      af[0] = *(const s16x8*)(ab_); \
      af[1] = *(const s16x8*)(ab_ + 512); \
      af[2] = *(const s16x8*)(ab_ + 1024); \
      af[3] = *(const s16x8*)(ab_ + 1536); \
      const u16* bb_ = &Bs[buf][kk][(wn + laneh) * 32 + aswz]; \
      bf[0] = *(const s16x8*)(bb_); \
      bf[1] = *(const s16x8*)(bb_ + 512); \
      bf[2] = *(const s16x8*)(bb_ + 1024); \
      bf[3] = *(const s16x8*)(bb_ + 1536); } \
    STAGE; \
    __builtin_amdgcn_s_barrier(); \
    asm volatile("s_waitcnt lgkmcnt(0)" ::: "memory"); \
    __builtin_amdgcn_sched_barrier(0); \
    __builtin_amdgcn_s_setprio(1); \
    _Pragma("unroll") \
    for (int i2 = 0; i2 < 4; ++i2) \
      _Pragma("unroll") \
      for (int j2 = 0; j2 < 4; ++j2) \
        acc[i2][j2] = __builtin_amdgcn_mfma_f32_16x16x32_bf16( \
            af[i2], bf[j2], acc[i2][j2], 0, 0, 0); \
    __builtin_amdgcn_s_setprio(0); \
    GATE; \
    __builtin_amdgcn_s_barrier(); \
  } while (0)

__global__ __launch_bounds__(512, 2) void gemm_pv(
    const u16* __restrict__ A, const u16* __restrict__ Bt,
    float* __restrict__ C, const float* __restrict__ xres,
    const float* __restrict__ invs, int M, int N, int Kd) {
  __shared__ u16 As[2][2][256 * 32];  // 64 KiB
  __shared__ u16 Bs[2][2][128 * 32];  // 32 KiB

  // XCD-local A-panel mapping: xcd x -> bm in [4x,4x+4), bn 0..7
  int bid = blockIdx.x;
  int bm = (bid & 7) * 4 + ((bid >> 3) & 3);
  int bn = bid >> 5;
  size_t m0 = (size_t)bm << 8;
  size_t n0 = (size_t)bn << 7;

  int tid = threadIdx.x;
  int lane = tid & 63;
  int wave = tid >> 6;
  int wm = (wave >> 1) * 64;  // 4 M-waves
  int wn = (wave & 1) * 64;   // 2 N-waves
  int laneh = lane & 15;
  int lanev = lane >> 4;
  int aswz = ((lanev ^ ((laneh >> 1) & 3)) << 3);

  int prow = tid >> 2;
  int lslot = (tid & 3) ^ ((tid >> 3) & 3);
  const u16* Asrc = A + (m0 + prow) * Kd + lslot * 8;
  const u16* Bsrc = Bt + (n0 + prow) * Kd + lslot * 8;
  size_t srow128 = (size_t)128 * Kd;

  f32x4 acc[4][4] = {};
  s16x8 af[4], bf[4];

  PSTG(0, 0, 0); PSTG(0, 1, 0); PSTG(1, 0, 1);
  GATE6;
  __builtin_amdgcn_s_barrier();

  int NI = Kd >> 7;
  for (int it = 0; it < NI - 1; ++it) {
    int t = 2 * it;
    PPHASE(0, 0, PSTG(1, 1, t + 1), GATE6);
    PPHASE(0, 1, PSTG(0, 0, t + 2), GATE6);
    PPHASE(1, 0, PSTG(0, 1, t + 2), GATE6);
    PPHASE(1, 1, PSTG(1, 0, t + 3), GATE6);
  }
  {
    int t = 2 * (NI - 1);
    PPHASE(0, 0, PSTG(1, 1, t + 1), GATE6);
    PPHASE(0, 1, NOSTG, GATE3);
    PPHASE(1, 0, NOSTG, GATE0);
    PPHASE(1, 1, NOSTG, NOGATE);
  }

  int crow = (int)m0 + wm + (lanev << 2);
  int ccol = (int)n0 + wn + laneh;
#pragma unroll
  for (int mi = 0; mi < 4; ++mi)
#pragma unroll
    for (int r = 0; r < 4; ++r) {
      int row = crow + mi * 16 + r;
      float inv = invs[row];
      size_t rbase = (size_t)row * N + ccol;
#pragma unroll
      for (int ni = 0; ni < 4; ++ni)
        C[rbase + ni * 16] = xres[rbase + ni * 16] + acc[mi][ni][r] * inv;
    }
}

// ---------------- NT GEMM: C[M][N] = A[M][K] * Bt[N][K]^T (128^2) -----------
// EPI: 0 = bf16 store (+bias aux1), 1 = transposed bf16 store (+bias aux1)
template <int EPI>
__global__ __launch_bounds__(256) void gemm_nt(
    const u16* __restrict__ A, const u16* __restrict__ Bt,
    void* __restrict__ Cout, int M, int N, int K,
    const float* __restrict__ aux1, const float* __restrict__ aux2) {
  constexpr int BK = 64;
  __shared__ u16 As[128 * BK];
  __shared__ u16 Bs[128 * BK];

  int nwg = gridDim.x;
  int bid = blockIdx.x;
  int swz = ((nwg & 7) == 0) ? ((bid & 7) * (nwg >> 3) + (bid >> 3)) : bid;
  int nbm = M >> 7;
  int bm = swz % nbm;
  int bn = swz / nbm;

  int tid = threadIdx.x;
  int lane = tid & 63;
  int wave = tid >> 6;
  int wm = (wave >> 1) << 6;
  int wn = (wave & 1) << 6;
  size_t m0 = (size_t)bm << 7;
  size_t n0 = (size_t)bn << 7;

  int srow = tid >> 3;
  int scol = (tid & 7) << 3;

  f32x4 acc[4][4] = {};

  const u16* Ag = A + (m0 + srow) * K + scol;
  const u16* Bg = Bt + (n0 + srow) * K + scol;
  u16* Asw = &As[wave * 512];
  u16* Bsw = &Bs[wave * 512];

  int laneh = lane & 15;
  int lanev = lane >> 4;

  for (int k0 = 0; k0 < K; k0 += BK) {
#pragma unroll
    for (int i = 0; i < 4; ++i) {
      gload_lds16(Ag + (size_t)i * 32 * K + k0, Asw + i * 2048);
      gload_lds16(Bg + (size_t)i * 32 * K + k0, Bsw + i * 2048);
    }
    __syncthreads();
#pragma unroll
    for (int kk = 0; kk < 2; ++kk) {
      s16x8 af[4], bfr[4];
#pragma unroll
      for (int i = 0; i < 4; ++i) {
        af[i]  = *(const s16x8*)&As[(wm + i * 16 + laneh) * BK + kk * 32 + lanev * 8];
        bfr[i] = *(const s16x8*)&Bs[(wn + i * 16 + laneh) * BK + kk * 32 + lanev * 8];
      }
#pragma unroll
      for (int mi = 0; mi < 4; ++mi)
#pragma unroll
        for (int ni = 0; ni < 4; ++ni)
          acc[mi][ni] = __builtin_amdgcn_mfma_f32_16x16x32_bf16(
              af[mi], bfr[ni], acc[mi][ni], 0, 0, 0);
    }
    __syncthreads();
  }

  int crow = (int)m0 + wm + (lanev << 2);
  int ccol = (int)n0 + wn + laneh;

  if constexpr (EPI == 0) {
    u16* C = (u16*)Cout;
#pragma unroll
    for (int mi = 0; mi < 4; ++mi)
#pragma unroll
      for (int r = 0; r < 4; ++r) {
        size_t row = (size_t)(crow + mi * 16 + r);
#pragma unroll
        for (int ni = 0; ni < 4; ++ni)
          C[row * N + ccol + ni * 16] = f2bf(acc[mi][ni][r] + aux1[ccol + ni * 16]);
      }
  } else {
    u16* C = (u16*)Cout;  // [N][M]
#pragma unroll
    for (int ni = 0; ni < 4; ++ni) {
      float b = aux1[ccol + ni * 16];
#pragma unroll
      for (int mi = 0; mi < 4; ++mi) {
        s16x4 v;
#pragma unroll
        for (int r = 0; r < 4; ++r) v[r] = (short)f2bf(acc[mi][ni][r] + b);
        *(s16x4*)&C[(size_t)(ccol + ni * 16) * M + crow + mi * 16] = v;
      }
    }
  }
}

extern "C" void kernel_launch(void* const* d_in, const int* in_sizes, int n_in,
                              void* d_out, int out_size, void* d_ws, size_t ws_size,
                              hipStream_t stream) {
  const float* x  = (const float*)d_in[0];
  const float* mb = (const float*)d_in[1];
  const float* Wq = (const float*)d_in[2];
  const float* bq = (const float*)d_in[3];
  const float* Wk = (const float*)d_in[4];
  const float* bk = (const float*)d_in[5];
  const float* Wv = (const float*)d_in[6];
  const float* bv = (const float*)d_in[7];
  float* out = (float*)d_out;

  const int B = 8192, H = 1024, Mm = 4096;

  char* ws = (char*)d_ws;
  u16* xb  = (u16*)ws; ws += (size_t)B * H * 2;
  u16* mbb = (u16*)ws; ws += (size_t)Mm * H * 2;
  u16* Wqt = (u16*)ws; ws += (size_t)H * H * 2;
  u16* Wkt = (u16*)ws; ws += (size_t)H * H * 2;
  u16* Wvt = (u16*)ws; ws += (size_t)H * H * 2;
  u16* Q   = (u16*)ws; ws += (size_t)B * H * 2;
  u16* Kp  = (u16*)ws; ws += (size_t)Mm * H * 2;
  u16* Vt  = (u16*)ws; ws += (size_t)H * Mm * 2;
  u16* S   = (u16*)ws; ws += (size_t)B * Mm * 2;
  float* invs = (float*)ws;

  cast_bf16_kernel<<<2048, 256, 0, stream>>>(x, xb, B * H / 8);
  cast_bf16_kernel<<<1024, 256, 0, stream>>>(mb, mbb, Mm * H / 8);
  tcast_kernel<<<(H / 32) * (H / 32), 256, 0, stream>>>(Wq, Wqt, H, H);
  tcast_kernel<<<(H / 32) * (H / 32), 256, 0, stream>>>(Wk, Wkt, H, H);
  tcast_kernel<<<(H / 32) * (H / 32), 256, 0, stream>>>(Wv, Wvt, H, H);

  gemm_nt<0><<<(B / 128) * (H / 128), 256, 0, stream>>>(xb, Wqt, Q, B, H, H, bq, nullptr);
  gemm_nt<0><<<(Mm / 128) * (H / 128), 256, 0, stream>>>(mbb, Wkt, Kp, Mm, H, H, bk, nullptr);
  gemm_nt<1><<<(Mm / 128) * (H / 128), 256, 0, stream>>>(mbb, Wvt, Vt, Mm, H, H, bv, nullptr);

  gemm_qkt_exp<<<(B / 256) * (Mm / 256), 512, 0, stream>>>(Q, Kp, S, B, Mm, H);

  rowsum_inv_kernel<<<B, 256, 0, stream>>>(S, invs, Mm);

  gemm_pv<<<(B / 256) * (H / 128), 512, 0, stream>>>(S, Vt, out, x, invs, B, H, Mm);
}

// Round 4
// 251.088 us; speedup vs baseline: 1.2271x; 1.0670x over previous
//
#include <hip/hip_runtime.h>
#include <stdint.h>

typedef unsigned short u16;
using f32x4 = __attribute__((ext_vector_type(4))) float;
using s16x8 = __attribute__((ext_vector_type(8))) short;
using s16x4 = __attribute__((ext_vector_type(4))) short;

__device__ __forceinline__ float bf2f(u16 u) {
  union { uint32_t u; float f; } v; v.u = ((uint32_t)u) << 16; return v.f;
}
__device__ __forceinline__ u16 f2bf(float f) {
  union { float f; uint32_t u; } v; v.f = f;
  uint32_t u = v.u;
  return (u16)((u + 0x7fffu + ((u >> 16) & 1u)) >> 16);
}

__device__ __forceinline__ void gload_lds16(const void* g, void* l) {
  __builtin_amdgcn_global_load_lds(
      (const __attribute__((address_space(1))) void*)g,
      (__attribute__((address_space(3))) void*)l, 16, 0, 0);
}

// opaque LDS b128 read: compiler cannot connect it to global_load_lds, so it
// cannot insert its own vmcnt(0) drains; our counted gates order the pipe.
#define DSRO(dst, base, offbytes) \
  asm volatile("ds_read_b128 %0, %1 offset:%2" : "=v"(dst) : "v"(base), "i"(offbytes))

// ---------------- cast f32 -> bf16 (vectorized, grid-stride) ----------------
__global__ __launch_bounds__(256) void cast_bf16_kernel(
    const float* __restrict__ in, u16* __restrict__ out, int n8) {
  int idx = blockIdx.x * blockDim.x + threadIdx.x;
  int stride = gridDim.x * blockDim.x;
  for (int i = idx; i < n8; i += stride) {
    const float4* p = (const float4*)(in + (size_t)i * 8);
    float4 a = p[0], b = p[1];
    s16x8 o;
    o[0] = (short)f2bf(a.x); o[1] = (short)f2bf(a.y);
    o[2] = (short)f2bf(a.z); o[3] = (short)f2bf(a.w);
    o[4] = (short)f2bf(b.x); o[5] = (short)f2bf(b.y);
    o[6] = (short)f2bf(b.z); o[7] = (short)f2bf(b.w);
    *(s16x8*)(out + (size_t)i * 8) = o;
  }
}

// ------------- transpose-cast: W[K][N] f32 -> Wt[N][K] bf16 -----------------
__global__ __launch_bounds__(256) void tcast_kernel(
    const float* __restrict__ W, u16* __restrict__ Wt, int Kd, int Nd) {
  __shared__ u16 tile[32][33];
  int nbx = Nd / 32;
  int bx = blockIdx.x % nbx;
  int by = blockIdx.x / nbx;
  int tr = threadIdx.x >> 5;
  int tc = threadIdx.x & 31;
#pragma unroll
  for (int i = 0; i < 4; ++i)
    tile[tr + i * 8][tc] = f2bf(W[(size_t)(by * 32 + tr + i * 8) * Nd + bx * 32 + tc]);
  __syncthreads();
#pragma unroll
  for (int i = 0; i < 4; ++i)
    Wt[(size_t)(bx * 32 + tr + i * 8) * Kd + by * 32 + tc] = tile[tc][tr + i * 8];
}

// ---------------- row sums of exp-scores -> reciprocal ----------------------
__global__ __launch_bounds__(256) void rowsum_inv_kernel(
    const u16* __restrict__ S, float* __restrict__ invsum, int Ncols) {
  int row = blockIdx.x;
  const s16x8* p = (const s16x8*)(S + (size_t)row * Ncols);
  int n8 = Ncols >> 3;
  float s = 0.f;
  for (int i = threadIdx.x; i < n8; i += 256) {
    s16x8 v = p[i];
#pragma unroll
    for (int j = 0; j < 8; ++j) s += bf2f((u16)v[j]);
  }
#pragma unroll
  for (int off = 32; off > 0; off >>= 1) s += __shfl_down(s, off, 64);
  __shared__ float red[4];
  int lane = threadIdx.x & 63, wave = threadIdx.x >> 6;
  if (lane == 0) red[wave] = s;
  __syncthreads();
  if (threadIdx.x == 0) invsum[row] = 1.f / (red[0] + red[1] + red[2] + red[3]);
}

// ============================ gate macros ===================================
#define GATE8 asm volatile("s_waitcnt vmcnt(8)" ::: "memory")
#define GATE6 asm volatile("s_waitcnt vmcnt(6)" ::: "memory")
#define GATE4 asm volatile("s_waitcnt vmcnt(4)" ::: "memory")
#define GATE3 asm volatile("s_waitcnt vmcnt(3)" ::: "memory")
#define GATE0 asm volatile("s_waitcnt vmcnt(0)" ::: "memory")
#define NOGATE (void)0
#define NOSTG (void)0

// ======================= 8-phase 256x256 QK^T kernel ========================
// C[M][N] = exp((A[M][K] @ Bt[N][K]^T) / 32) in bf16.

#define STG_A(buf, h, kt) do { \
    const u16* s_ = Asrc + (size_t)(kt) * 64 + (h) * 32; \
    gload_lds16(s_, &As[buf][h][wave * 512]); \
    gload_lds16(s_ + srow128, &As[buf][h][wave * 512 + 4096]); \
  } while (0)

#define STG_B(buf, h, kt) do { \
    const u16* s_ = Bsrc + (size_t)(kt) * 64 + (h) * 32; \
    gload_lds16(s_, &Bs[buf][h][wave * 512]); \
    gload_lds16(s_ + srow128, &Bs[buf][h][wave * 512 + 4096]); \
  } while (0)

#define DS_FRAGS(buf, kk, mh) do { \
    DSRO(af[0], aB[buf][kk], (mh) * 4096 + 0); \
    DSRO(af[1], aB[buf][kk], (mh) * 4096 + 1024); \
    DSRO(af[2], aB[buf][kk], (mh) * 4096 + 2048); \
    DSRO(af[3], aB[buf][kk], (mh) * 4096 + 3072); \
    if ((mh) == 0) { \
      DSRO(bf[0], bB[buf][kk], 0); \
      DSRO(bf[1], bB[buf][kk], 1024); \
      DSRO(bf[2], bB[buf][kk], 2048); \
      DSRO(bf[3], bB[buf][kk], 3072); \
    } \
  } while (0)

#define PHASE(buf, kk, mh, STAGE, GATE) do { \
    DS_FRAGS(buf, kk, mh); \
    STAGE; \
    __builtin_amdgcn_s_barrier(); \
    asm volatile("s_waitcnt lgkmcnt(0)" ::: "memory"); \
    __builtin_amdgcn_sched_barrier(0); \
    __builtin_amdgcn_s_setprio(1); \
    _Pragma("unroll") \
    for (int i2 = 0; i2 < 4; ++i2) \
      _Pragma("unroll") \
      for (int j2 = 0; j2 < 4; ++j2) \
        acc[(mh) * 4 + i2][j2] = __builtin_amdgcn_mfma_f32_16x16x32_bf16( \
            af[i2], bf[j2], acc[(mh) * 4 + i2][j2], 0, 0, 0); \
    __builtin_amdgcn_s_setprio(0); \
    GATE; \
    __builtin_amdgcn_s_barrier(); \
  } while (0)

__global__ __launch_bounds__(512, 2) void gemm_qkt_exp(
    const u16* __restrict__ A, const u16* __restrict__ Bt, u16* __restrict__ C,
    int M, int N, int Kd) {
  __shared__ u16 As[2][2][256 * 32];
  __shared__ u16 Bs[2][2][256 * 32];

  int nwg = gridDim.x;
  int bid = blockIdx.x;
  int swz = ((nwg & 7) == 0) ? ((bid & 7) * (nwg >> 3) + (bid >> 3)) : bid;
  int nbm = M >> 8;
  int bm = swz % nbm;
  int bn = swz / nbm;
  size_t m0 = (size_t)bm << 8;
  size_t n0 = (size_t)bn << 8;

  int tid = threadIdx.x;
  int lane = tid & 63;
  int wave = tid >> 6;
  int wm = (wave >> 2) * 128;
  int wn = (wave & 3) * 64;
  int laneh = lane & 15;
  int lanev = lane >> 4;
  int aswz = ((lanev ^ ((laneh >> 1) & 3)) << 3);

  int prow = tid >> 2;
  int lslot = (tid & 3) ^ ((tid >> 3) & 3);
  const u16* Asrc = A + (m0 + prow) * Kd + lslot * 8;
  const u16* Bsrc = Bt + (n0 + prow) * Kd + lslot * 8;
  size_t srow128 = (size_t)128 * Kd;

  // precomputed 32-bit LDS base addresses for opaque ds_reads
  uint32_t aB[2][2], bB[2][2];
#pragma unroll
  for (int b = 0; b < 2; ++b)
#pragma unroll
    for (int k2 = 0; k2 < 2; ++k2) {
      aB[b][k2] = (uint32_t)(uintptr_t)&As[b][k2][(wm + laneh) * 32 + aswz];
      bB[b][k2] = (uint32_t)(uintptr_t)&Bs[b][k2][(wn + laneh) * 32 + aswz];
    }

  f32x4 acc[8][4] = {};
  s16x8 af[4], bf[4];

  STG_A(0, 0, 0); STG_B(0, 0, 0);
  STG_A(0, 1, 0); STG_B(0, 1, 0);
  STG_A(1, 0, 1); STG_B(1, 0, 1);
  GATE4;
  __builtin_amdgcn_s_barrier();

  int NI = Kd >> 7;
  for (int it = 0; it < NI - 1; ++it) {
    int t = 2 * it;
    PHASE(0, 0, 0, STG_A(1, 1, t + 1), NOGATE);
    PHASE(0, 0, 1, STG_B(1, 1, t + 1), GATE8);
    PHASE(0, 1, 0, STG_A(0, 0, t + 2), NOGATE);
    PHASE(0, 1, 1, STG_B(0, 0, t + 2), GATE8);
    PHASE(1, 0, 0, STG_A(0, 1, t + 2), NOGATE);
    PHASE(1, 0, 1, STG_B(0, 1, t + 2), GATE8);
    PHASE(1, 1, 0, STG_A(1, 0, t + 3), NOGATE);
    PHASE(1, 1, 1, STG_B(1, 0, t + 3), GATE8);
  }
  {
    int t = 2 * (NI - 1);
    PHASE(0, 0, 0, STG_A(1, 1, t + 1), NOGATE);
    PHASE(0, 0, 1, STG_B(1, 1, t + 1), GATE8);
    PHASE(0, 1, 0, NOSTG, NOGATE);
    PHASE(0, 1, 1, NOSTG, GATE4);
    PHASE(1, 0, 0, NOSTG, NOGATE);
    PHASE(1, 0, 1, NOSTG, GATE0);
    PHASE(1, 1, 0, NOSTG, NOGATE);
    PHASE(1, 1, 1, NOSTG, NOGATE);
  }

  // ---- epilogue: exp(acc/32) -> bf16, packed stores via per-wave LDS bounce
  // All waves synced by final PHASE barrier; As is dead; reuse it.
  u16* epw = ((u16*)As) + wave * 1152;  // [16][72] u16, 16B-aligned rows
#pragma unroll
  for (int a = 0; a < 8; ++a) {
#pragma unroll
    for (int r = 0; r < 4; ++r)
#pragma unroll
      for (int j = 0; j < 4; ++j)
        epw[(lanev * 4 + r) * 72 + laneh + j * 16] =
            f2bf(__expf(acc[a][j][r] * 0.03125f));
    int rowoff = ((a >> 2) * 64) + ((a & 3) * 16);
#pragma unroll
    for (int p = 0; p < 2; ++p) {
      s16x8 v = *(const s16x8*)&epw[((lane >> 3) + 8 * p) * 72 + (lane & 7) * 8];
      size_t grow = m0 + wm + rowoff + (lane >> 3) + 8 * p;
      *(s16x8*)&C[grow * N + n0 + wn + (lane & 7) * 8] = v;
    }
  }
}

// ====================== 4-phase 256x128 PV kernel ===========================
// C[M][N] f32 = xres + (A[M][K]bf16 @ Bt[N][K]^T) * invs[row]

#define PSTG(buf, h, kt) do { \
    const u16* sa_ = Asrc + (size_t)(kt) * 64 + (h) * 32; \
    gload_lds16(sa_, &As[buf][h][wave * 512]); \
    gload_lds16(sa_ + srow128, &As[buf][h][wave * 512 + 4096]); \
    const u16* sb_ = Bsrc + (size_t)(kt) * 64 + (h) * 32; \
    gload_lds16(sb_, &Bs[buf][h][wave * 512]); \
  } while (0)

#define PPHASE(buf, kk, STAGE, GATE) do { \
    DSRO(af[0], pA[buf][kk], 0); \
    DSRO(af[1], pA[buf][kk], 1024); \
    DSRO(af[2], pA[buf][kk], 2048); \
    DSRO(af[3], pA[buf][kk], 3072); \
    DSRO(bf[0], pB[buf][kk], 0); \
    DSRO(bf[1], pB[buf][kk], 1024); \
    DSRO(bf[2], pB[buf][kk], 2048); \
    DSRO(bf[3], pB[buf][kk], 3072); \
    STAGE; \
    __builtin_amdgcn_s_barrier(); \
    asm volatile("s_waitcnt lgkmcnt(0)" ::: "memory"); \
    __builtin_amdgcn_sched_barrier(0); \
    __builtin_amdgcn_s_setprio(1); \
    _Pragma("unroll") \
    for (int i2 = 0; i2 < 4; ++i2) \
      _Pragma("unroll") \
      for (int j2 = 0; j2 < 4; ++j2) \
        acc[i2][j2] = __builtin_amdgcn_mfma_f32_16x16x32_bf16( \
            af[i2], bf[j2], acc[i2][j2], 0, 0, 0); \
    __builtin_amdgcn_s_setprio(0); \
    GATE; \
    __builtin_amdgcn_s_barrier(); \
  } while (0)

__global__ __launch_bounds__(512, 2) void gemm_pv(
    const u16* __restrict__ A, const u16* __restrict__ Bt,
    float* __restrict__ C, const float* __restrict__ xres,
    const float* __restrict__ invs, int M, int N, int Kd) {
  __shared__ u16 As[2][2][256 * 32];  // 64 KiB
  __shared__ u16 Bs[2][2][128 * 32];  // 32 KiB

  int bid = blockIdx.x;
  int bm = (bid & 7) * 4 + ((bid >> 3) & 3);
  int bn = bid >> 5;
  size_t m0 = (size_t)bm << 8;
  size_t n0 = (size_t)bn << 7;

  int tid = threadIdx.x;
  int lane = tid & 63;
  int wave = tid >> 6;
  int wm = (wave >> 1) * 64;
  int wn = (wave & 1) * 64;
  int laneh = lane & 15;
  int lanev = lane >> 4;
  int aswz = ((lanev ^ ((laneh >> 1) & 3)) << 3);

  int prow = tid >> 2;
  int lslot = (tid & 3) ^ ((tid >> 3) & 3);
  const u16* Asrc = A + (m0 + prow) * Kd + lslot * 8;
  const u16* Bsrc = Bt + (n0 + prow) * Kd + lslot * 8;
  size_t srow128 = (size_t)128 * Kd;

  uint32_t pA[2][2], pB[2][2];
#pragma unroll
  for (int b = 0; b < 2; ++b)
#pragma unroll
    for (int k2 = 0; k2 < 2; ++k2) {
      pA[b][k2] = (uint32_t)(uintptr_t)&As[b][k2][(wm + laneh) * 32 + aswz];
      pB[b][k2] = (uint32_t)(uintptr_t)&Bs[b][k2][(wn + laneh) * 32 + aswz];
    }

  f32x4 acc[4][4] = {};
  s16x8 af[4], bf[4];

  PSTG(0, 0, 0); PSTG(0, 1, 0); PSTG(1, 0, 1);
  GATE6;
  __builtin_amdgcn_s_barrier();

  int NI = Kd >> 7;
  for (int it = 0; it < NI - 1; ++it) {
    int t = 2 * it;
    PPHASE(0, 0, PSTG(1, 1, t + 1), GATE6);
    PPHASE(0, 1, PSTG(0, 0, t + 2), GATE6);
    PPHASE(1, 0, PSTG(0, 1, t + 2), GATE6);
    PPHASE(1, 1, PSTG(1, 0, t + 3), GATE6);
  }
  {
    int t = 2 * (NI - 1);
    PPHASE(0, 0, PSTG(1, 1, t + 1), GATE6);
    PPHASE(0, 1, NOSTG, GATE3);
    PPHASE(1, 0, NOSTG, GATE0);
    PPHASE(1, 1, NOSTG, NOGATE);
  }

  int crow = (int)m0 + wm + (lanev << 2);
  int ccol = (int)n0 + wn + laneh;
#pragma unroll
  for (int mi = 0; mi < 4; ++mi)
#pragma unroll
    for (int r = 0; r < 4; ++r) {
      int row = crow + mi * 16 + r;
      float inv = invs[row];
      size_t rbase = (size_t)row * N + ccol;
#pragma unroll
      for (int ni = 0; ni < 4; ++ni)
        C[rbase + ni * 16] = xres[rbase + ni * 16] + acc[mi][ni][r] * inv;
    }
}

// ---------------- NT GEMM: C[M][N] = A[M][K] * Bt[N][K]^T (128^2) -----------
// EPI: 0 = bf16 store (+bias aux1), 1 = transposed bf16 store (+bias aux1)
template <int EPI>
__global__ __launch_bounds__(256) void gemm_nt(
    const u16* __restrict__ A, const u16* __restrict__ Bt,
    void* __restrict__ Cout, int M, int N, int K,
    const float* __restrict__ aux1) {
  constexpr int BK = 64;
  __shared__ u16 As[128 * BK];
  __shared__ u16 Bs[128 * BK];

  int nwg = gridDim.x;
  int bid = blockIdx.x;
  int swz = ((nwg & 7) == 0) ? ((bid & 7) * (nwg >> 3) + (bid >> 3)) : bid;
  int nbm = M >> 7;
  int bm = swz % nbm;
  int bn = swz / nbm;

  int tid = threadIdx.x;
  int lane = tid & 63;
  int wave = tid >> 6;
  int wm = (wave >> 1) << 6;
  int wn = (wave & 1) << 6;
  size_t m0 = (size_t)bm << 7;
  size_t n0 = (size_t)bn << 7;

  int srow = tid >> 3;
  int scol = (tid & 7) << 3;

  f32x4 acc[4][4] = {};

  const u16* Ag = A + (m0 + srow) * K + scol;
  const u16* Bg = Bt + (n0 + srow) * K + scol;
  u16* Asw = &As[wave * 512];
  u16* Bsw = &Bs[wave * 512];

  int laneh = lane & 15;
  int lanev = lane >> 4;

  for (int k0 = 0; k0 < K; k0 += BK) {
#pragma unroll
    for (int i = 0; i < 4; ++i) {
      gload_lds16(Ag + (size_t)i * 32 * K + k0, Asw + i * 2048);
      gload_lds16(Bg + (size_t)i * 32 * K + k0, Bsw + i * 2048);
    }
    __syncthreads();
#pragma unroll
    for (int kk = 0; kk < 2; ++kk) {
      s16x8 af[4], bfr[4];
#pragma unroll
      for (int i = 0; i < 4; ++i) {
        af[i]  = *(const s16x8*)&As[(wm + i * 16 + laneh) * BK + kk * 32 + lanev * 8];
        bfr[i] = *(const s16x8*)&Bs[(wn + i * 16 + laneh) * BK + kk * 32 + lanev * 8];
      }
#pragma unroll
      for (int mi = 0; mi < 4; ++mi)
#pragma unroll
        for (int ni = 0; ni < 4; ++ni)
          acc[mi][ni] = __builtin_amdgcn_mfma_f32_16x16x32_bf16(
              af[mi], bfr[ni], acc[mi][ni], 0, 0, 0);
    }
    __syncthreads();
  }

  int crow = (int)m0 + wm + (lanev << 2);
  int ccol = (int)n0 + wn + laneh;

  if constexpr (EPI == 0) {
    u16* C = (u16*)Cout;
#pragma unroll
    for (int mi = 0; mi < 4; ++mi)
#pragma unroll
      for (int r = 0; r < 4; ++r) {
        size_t row = (size_t)(crow + mi * 16 + r);
#pragma unroll
        for (int ni = 0; ni < 4; ++ni)
          C[row * N + ccol + ni * 16] = f2bf(acc[mi][ni][r] + aux1[ccol + ni * 16]);
      }
  } else {
    u16* C = (u16*)Cout;  // [N][M]
#pragma unroll
    for (int ni = 0; ni < 4; ++ni) {
      float b = aux1[ccol + ni * 16];
#pragma unroll
      for (int mi = 0; mi < 4; ++mi) {
        s16x4 v;
#pragma unroll
        for (int r = 0; r < 4; ++r) v[r] = (short)f2bf(acc[mi][ni][r] + b);
        *(s16x4*)&C[(size_t)(ccol + ni * 16) * M + crow + mi * 16] = v;
      }
    }
  }
}

extern "C" void kernel_launch(void* const* d_in, const int* in_sizes, int n_in,
                              void* d_out, int out_size, void* d_ws, size_t ws_size,
                              hipStream_t stream) {
  const float* x  = (const float*)d_in[0];
  const float* mb = (const float*)d_in[1];
  const float* Wq = (const float*)d_in[2];
  const float* bq = (const float*)d_in[3];
  const float* Wk = (const float*)d_in[4];
  const float* bk = (const float*)d_in[5];
  const float* Wv = (const float*)d_in[6];
  const float* bv = (const float*)d_in[7];
  float* out = (float*)d_out;

  const int B = 8192, H = 1024, Mm = 4096;

  char* ws = (char*)d_ws;
  u16* xb  = (u16*)ws; ws += (size_t)B * H * 2;
  u16* mbb = (u16*)ws; ws += (size_t)Mm * H * 2;
  u16* Wqt = (u16*)ws; ws += (size_t)H * H * 2;
  u16* Wkt = (u16*)ws; ws += (size_t)H * H * 2;
  u16* Wvt = (u16*)ws; ws += (size_t)H * H * 2;
  u16* Q   = (u16*)ws; ws += (size_t)B * H * 2;
  u16* Kp  = (u16*)ws; ws += (size_t)Mm * H * 2;
  u16* Vt  = (u16*)ws; ws += (size_t)H * Mm * 2;
  u16* S   = (u16*)ws; ws += (size_t)B * Mm * 2;
  float* invs = (float*)ws;

  cast_bf16_kernel<<<2048, 256, 0, stream>>>(x, xb, B * H / 8);
  cast_bf16_kernel<<<1024, 256, 0, stream>>>(mb, mbb, Mm * H / 8);
  tcast_kernel<<<(H / 32) * (H / 32), 256, 0, stream>>>(Wq, Wqt, H, H);
  tcast_kernel<<<(H / 32) * (H / 32), 256, 0, stream>>>(Wk, Wkt, H, H);
  tcast_kernel<<<(H / 32) * (H / 32), 256, 0, stream>>>(Wv, Wvt, H, H);

  gemm_nt<0><<<(B / 128) * (H / 128), 256, 0, stream>>>(xb, Wqt, Q, B, H, H, bq);
  gemm_nt<0><<<(Mm / 128) * (H / 128), 256, 0, stream>>>(mbb, Wkt, Kp, Mm, H, H, bk);
  gemm_nt<1><<<(Mm / 128) * (H / 128), 256, 0, stream>>>(mbb, Wvt, Vt, Mm, H, H, bv);

  gemm_qkt_exp<<<(B / 256) * (Mm / 256), 512, 0, stream>>>(Q, Kp, S, B, Mm, H);

  rowsum_inv_kernel<<<B, 256, 0, stream>>>(S, invs, Mm);

  gemm_pv<<<(B / 256) * (H / 128), 512, 0, stream>>>(S, Vt, out, x, invs, B, H, Mm);
}

// Round 5
// 243.084 us; speedup vs baseline: 1.2675x; 1.0329x over previous
//
#include <hip/hip_runtime.h>
#include <stdint.h>

typedef unsigned short u16;
using f32x4 = __attribute__((ext_vector_type(4))) float;
using s16x8 = __attribute__((ext_vector_type(8))) short;
using s16x4 = __attribute__((ext_vector_type(4))) short;

__device__ __forceinline__ float bf2f(u16 u) {
  union { uint32_t u; float f; } v; v.u = ((uint32_t)u) << 16; return v.f;
}
__device__ __forceinline__ u16 f2bf(float f) {
  union { float f; uint32_t u; } v; v.f = f;
  uint32_t u = v.u;
  return (u16)((u + 0x7fffu + ((u >> 16) & 1u)) >> 16);
}

__device__ __forceinline__ void gload_lds16(const void* g, void* l) {
  __builtin_amdgcn_global_load_lds(
      (const __attribute__((address_space(1))) void*)g,
      (__attribute__((address_space(3))) void*)l, 16, 0, 0);
}

#define DSRO(dst, base, offbytes) \
  asm volatile("ds_read_b128 %0, %1 offset:%2" : "=v"(dst) : "v"(base), "i"(offbytes))

// ---------------- cast f32 -> bf16 (vectorized, grid-stride) ----------------
__global__ __launch_bounds__(256) void cast_bf16_kernel(
    const float* __restrict__ in, u16* __restrict__ out, int n8) {
  int idx = blockIdx.x * blockDim.x + threadIdx.x;
  int stride = gridDim.x * blockDim.x;
  for (int i = idx; i < n8; i += stride) {
    const float4* p = (const float4*)(in + (size_t)i * 8);
    float4 a = p[0], b = p[1];
    s16x8 o;
    o[0] = (short)f2bf(a.x); o[1] = (short)f2bf(a.y);
    o[2] = (short)f2bf(a.z); o[3] = (short)f2bf(a.w);
    o[4] = (short)f2bf(b.x); o[5] = (short)f2bf(b.y);
    o[6] = (short)f2bf(b.z); o[7] = (short)f2bf(b.w);
    *(s16x8*)(out + (size_t)i * 8) = o;
  }
}

// ------------- transpose-cast: W[K][N] f32 -> Wt[N][K] bf16 -----------------
__global__ __launch_bounds__(256) void tcast_kernel(
    const float* __restrict__ W, u16* __restrict__ Wt, int Kd, int Nd) {
  __shared__ u16 tile[32][33];
  int nbx = Nd / 32;
  int bx = blockIdx.x % nbx;
  int by = blockIdx.x / nbx;
  int tr = threadIdx.x >> 5;
  int tc = threadIdx.x & 31;
#pragma unroll
  for (int i = 0; i < 4; ++i)
    tile[tr + i * 8][tc] = f2bf(W[(size_t)(by * 32 + tr + i * 8) * Nd + bx * 32 + tc]);
  __syncthreads();
#pragma unroll
  for (int i = 0; i < 4; ++i)
    Wt[(size_t)(bx * 32 + tr + i * 8) * Kd + by * 32 + tc] = tile[tc][tr + i * 8];
}

// ============================ gate macros ===================================
#define GATE8 asm volatile("s_waitcnt vmcnt(8)" ::: "memory")
#define GATE6 asm volatile("s_waitcnt vmcnt(6)" ::: "memory")
#define GATE3 asm volatile("s_waitcnt vmcnt(3)" ::: "memory")
#define GATE0 asm volatile("s_waitcnt vmcnt(0)" ::: "memory")
#define NOGATE (void)0
#define NOSTG (void)0
#define LGKM0 asm volatile("s_waitcnt lgkmcnt(0)" ::: "memory")
#define SBAR __builtin_amdgcn_s_barrier()
#define SCHED0 __builtin_amdgcn_sched_barrier(0)

// ================= 8-phase 256x256 QK^T kernel (reg-pipelined) ==============
// C[M][N] = exp((A@Bt^T)/32) bf16; also atomicAdd per-row sums of C.

#define STG_A(buf, h, kt) do { \
    const u16* s_ = Asrc + (size_t)(kt) * 64 + (h) * 32; \
    gload_lds16(s_, &As[buf][h][wave * 512]); \
    gload_lds16(s_ + srow128, &As[buf][h][wave * 512 + 4096]); \
  } while (0)

#define STG_B(buf, h, kt) do { \
    const u16* s_ = Bsrc + (size_t)(kt) * 64 + (h) * 32; \
    gload_lds16(s_, &Bs[buf][h][wave * 512]); \
    gload_lds16(s_ + srow128, &Bs[buf][h][wave * 512 + 4096]); \
  } while (0)

#define QFRAG(NB_, NK_, NM_, NA_, NBF_, LB_) do { \
    DSRO(NA_[0], aB[NB_][NK_], (NM_) * 4096 + 0); \
    DSRO(NA_[1], aB[NB_][NK_], (NM_) * 4096 + 1024); \
    DSRO(NA_[2], aB[NB_][NK_], (NM_) * 4096 + 2048); \
    DSRO(NA_[3], aB[NB_][NK_], (NM_) * 4096 + 3072); \
    if (LB_) { \
      DSRO(NBF_[0], bB[NB_][NK_], 0); \
      DSRO(NBF_[1], bB[NB_][NK_], 1024); \
      DSRO(NBF_[2], bB[NB_][NK_], 2048); \
      DSRO(NBF_[3], bB[NB_][NK_], 3072); \
    } \
  } while (0)

#define QMFMA(MHC, CA_, CB_) do { \
    __builtin_amdgcn_s_setprio(1); \
    _Pragma("unroll") \
    for (int i2 = 0; i2 < 4; ++i2) \
      _Pragma("unroll") \
      for (int j2 = 0; j2 < 4; ++j2) \
        acc[(MHC) * 4 + i2][j2] = __builtin_amdgcn_mfma_f32_16x16x32_bf16( \
            CA_[i2], CB_[j2], acc[(MHC) * 4 + i2][j2], 0, 0, 0); \
    __builtin_amdgcn_s_setprio(0); \
  } while (0)

// phase p: prefetch frags for p+1 (coords NB_,NK_,NM_) into NA_/NBF_, stage,
// compute MFMA on CA_/CB_ (current), gate, barrier, drain prefetched reads.
#define QPH(MHC, CA_, CB_, NB_, NK_, NM_, NA_, NBF_, LB_, STAGE, GATE) do { \
    QFRAG(NB_, NK_, NM_, NA_, NBF_, LB_); \
    STAGE; \
    SCHED0; \
    QMFMA(MHC, CA_, CB_); \
    GATE; \
    SBAR; \
    LGKM0; \
    SCHED0; \
  } while (0)

__global__ __launch_bounds__(512, 2) void gemm_qkt_exp(
    const u16* __restrict__ A, const u16* __restrict__ Bt, u16* __restrict__ C,
    float* __restrict__ sums, int M, int N, int Kd) {
  __shared__ u16 As[2][2][256 * 32];
  __shared__ u16 Bs[2][2][256 * 32];

  int nwg = gridDim.x;
  int bid = blockIdx.x;
  int swz = ((nwg & 7) == 0) ? ((bid & 7) * (nwg >> 3) + (bid >> 3)) : bid;
  int nbm = M >> 8;
  int bm = swz % nbm;
  int bn = swz / nbm;
  size_t m0 = (size_t)bm << 8;
  size_t n0 = (size_t)bn << 8;

  int tid = threadIdx.x;
  int lane = tid & 63;
  int wave = tid >> 6;
  int wm = (wave >> 2) * 128;
  int wn = (wave & 3) * 64;
  int laneh = lane & 15;
  int lanev = lane >> 4;
  int aswz = ((lanev ^ ((laneh >> 1) & 3)) << 3);

  int prow = tid >> 2;
  int lslot = (tid & 3) ^ ((tid >> 3) & 3);
  const u16* Asrc = A + (m0 + prow) * Kd + lslot * 8;
  const u16* Bsrc = Bt + (n0 + prow) * Kd + lslot * 8;
  size_t srow128 = (size_t)128 * Kd;

  uint32_t aB[2][2], bB[2][2];
#pragma unroll
  for (int b = 0; b < 2; ++b)
#pragma unroll
    for (int k2 = 0; k2 < 2; ++k2) {
      aB[b][k2] = (uint32_t)(uintptr_t)&As[b][k2][(wm + laneh) * 32 + aswz];
      bB[b][k2] = (uint32_t)(uintptr_t)&Bs[b][k2][(wn + laneh) * 32 + aswz];
    }

  f32x4 acc[8][4] = {};
  s16x8 afA[4], afB[4], bfA[4], bfB[4];

  // prologue: stage 3 region-pairs, drain first pair, read P0 frags
  STG_A(0, 0, 0); STG_B(0, 0, 0);
  STG_A(0, 1, 0); STG_B(0, 1, 0);
  STG_A(1, 0, 1); STG_B(1, 0, 1);
  GATE8;
  SBAR;
  SCHED0;
  QFRAG(0, 0, 0, afA, bfA, 1);
  LGKM0;
  SCHED0;

  int NI = Kd >> 7;
  for (int it = 0; it < NI - 1; ++it) {
    int t = 2 * it;
    QPH(0, afA, bfA, 0, 0, 1, afB, bfA, 0, STG_A(1, 1, t + 1), GATE6);
    QPH(1, afB, bfA, 0, 1, 0, afA, bfB, 1, STG_B(1, 1, t + 1), GATE6);
    QPH(0, afA, bfB, 0, 1, 1, afB, bfB, 0, STG_A(0, 0, t + 2), GATE6);
    QPH(1, afB, bfB, 1, 0, 0, afA, bfA, 1, STG_B(0, 0, t + 2), GATE6);
    QPH(0, afA, bfA, 1, 0, 1, afB, bfA, 0, STG_A(0, 1, t + 2), GATE6);
    QPH(1, afB, bfA, 1, 1, 0, afA, bfB, 1, STG_B(0, 1, t + 2), GATE6);
    QPH(0, afA, bfB, 1, 1, 1, afB, bfB, 0, STG_A(1, 0, t + 3), GATE6);
    QPH(1, afB, bfB, 0, 0, 0, afA, bfA, 1, STG_B(1, 0, t + 3), GATE6);
  }
  {  // final iteration: stage only (1,1,t+1); drain
    int t = 2 * (NI - 1);
    QPH(0, afA, bfA, 0, 0, 1, afB, bfA, 0, STG_A(1, 1, t + 1), GATE6);
    QPH(1, afB, bfA, 0, 1, 0, afA, bfB, 1, STG_B(1, 1, t + 1), GATE6);
    QPH(0, afA, bfB, 0, 1, 1, afB, bfB, 0, NOSTG, GATE0);
    QPH(1, afB, bfB, 1, 0, 0, afA, bfA, 1, NOSTG, NOGATE);
    QPH(0, afA, bfA, 1, 0, 1, afB, bfA, 0, NOSTG, NOGATE);
    QPH(1, afB, bfA, 1, 1, 0, afA, bfB, 1, NOSTG, NOGATE);
    QPH(0, afA, bfB, 1, 1, 1, afB, bfB, 0, NOSTG, NOGATE);
    QMFMA(1, afB, bfB);
    SBAR;
  }

  // epilogue: exp -> bf16 store via per-wave LDS bounce + per-row atomic sums
  u16* epw = ((u16*)As) + wave * 1152;  // [16][72] u16
#pragma unroll
  for (int a = 0; a < 8; ++a) {
#pragma unroll
    for (int r = 0; r < 4; ++r)
#pragma unroll
      for (int j = 0; j < 4; ++j)
        epw[(lanev * 4 + r) * 72 + laneh + j * 16] =
            f2bf(__expf(acc[a][j][r] * 0.03125f));
    int rowoff = ((a >> 2) * 64) + ((a & 3) * 16);
#pragma unroll
    for (int p = 0; p < 2; ++p) {
      s16x8 v = *(const s16x8*)&epw[((lane >> 3) + 8 * p) * 72 + (lane & 7) * 8];
      size_t grow = m0 + wm + rowoff + (lane >> 3) + 8 * p;
      *(s16x8*)&C[grow * N + n0 + wn + (lane & 7) * 8] = v;
      float s = 0.f;
#pragma unroll
      for (int j = 0; j < 8; ++j) s += bf2f((u16)v[j]);
      s += __shfl_xor(s, 1, 64);
      s += __shfl_xor(s, 2, 64);
      s += __shfl_xor(s, 4, 64);
      if ((lane & 7) == 0) atomicAdd(&sums[grow], s);
    }
  }
}

// ============== 4-phase 256x128 pipelined GEMM (Q-proj / PV) ================
// EPI 0: C bf16 = acc + bias(aux).   EPI 3: C f32 = xres + acc / sums[row].

#define PSTG(buf, h, kt) do { \
    const u16* sa_ = Asrc + (size_t)(kt) * 64 + (h) * 32; \
    gload_lds16(sa_, &As[buf][h][wave * 512]); \
    gload_lds16(sa_ + srow128, &As[buf][h][wave * 512 + 4096]); \
    const u16* sb_ = Bsrc + (size_t)(kt) * 64 + (h) * 32; \
    gload_lds16(sb_, &Bs[buf][h][wave * 512]); \
  } while (0)

#define PFRAG(NB_, NK_, NA_, NBF_) do { \
    DSRO(NA_[0], pA[NB_][NK_], 0); \
    DSRO(NA_[1], pA[NB_][NK_], 1024); \
    DSRO(NA_[2], pA[NB_][NK_], 2048); \
    DSRO(NA_[3], pA[NB_][NK_], 3072); \
    DSRO(NBF_[0], pB[NB_][NK_], 0); \
    DSRO(NBF_[1], pB[NB_][NK_], 1024); \
    DSRO(NBF_[2], pB[NB_][NK_], 2048); \
    DSRO(NBF_[3], pB[NB_][NK_], 3072); \
  } while (0)

#define PMFMA(CA_, CB_) do { \
    __builtin_amdgcn_s_setprio(1); \
    _Pragma("unroll") \
    for (int i2 = 0; i2 < 4; ++i2) \
      _Pragma("unroll") \
      for (int j2 = 0; j2 < 4; ++j2) \
        acc[i2][j2] = __builtin_amdgcn_mfma_f32_16x16x32_bf16( \
            CA_[i2], CB_[j2], acc[i2][j2], 0, 0, 0); \
    __builtin_amdgcn_s_setprio(0); \
  } while (0)

#define PPH(CA_, CB_, NB_, NK_, NA_, NBF_, STAGE, GATE) do { \
    PFRAG(NB_, NK_, NA_, NBF_); \
    STAGE; \
    SCHED0; \
    PMFMA(CA_, CB_); \
    GATE; \
    SBAR; \
    LGKM0; \
    SCHED0; \
  } while (0)

template <int EPI>
__global__ __launch_bounds__(512, 2) void gemm_pipe(
    const u16* __restrict__ A, const u16* __restrict__ Bt,
    void* __restrict__ Cout, const float* __restrict__ aux,
    const float* __restrict__ xres, int M, int N, int Kd) {
  __shared__ u16 As[2][2][256 * 32];  // 64 KiB
  __shared__ u16 Bs[2][2][128 * 32];  // 32 KiB

  // XCD-local mapping: blocks sharing an A-panel land on one XCD
  int bid = blockIdx.x;
  int bm = (bid & 7) * 4 + ((bid >> 3) & 3);
  int bn = bid >> 5;
  size_t m0 = (size_t)bm << 8;
  size_t n0 = (size_t)bn << 7;

  int tid = threadIdx.x;
  int lane = tid & 63;
  int wave = tid >> 6;
  int wm = (wave >> 1) * 64;
  int wn = (wave & 1) * 64;
  int laneh = lane & 15;
  int lanev = lane >> 4;
  int aswz = ((lanev ^ ((laneh >> 1) & 3)) << 3);

  int prow = tid >> 2;
  int lslot = (tid & 3) ^ ((tid >> 3) & 3);
  const u16* Asrc = A + (m0 + prow) * Kd + lslot * 8;
  const u16* Bsrc = Bt + (n0 + prow) * Kd + lslot * 8;
  size_t srow128 = (size_t)128 * Kd;

  uint32_t pA[2][2], pB[2][2];
#pragma unroll
  for (int b = 0; b < 2; ++b)
#pragma unroll
    for (int k2 = 0; k2 < 2; ++k2) {
      pA[b][k2] = (uint32_t)(uintptr_t)&As[b][k2][(wm + laneh) * 32 + aswz];
      pB[b][k2] = (uint32_t)(uintptr_t)&Bs[b][k2][(wn + laneh) * 32 + aswz];
    }

  f32x4 acc[4][4] = {};
  s16x8 afA[4], afB[4], bfA[4], bfB[4];

  PSTG(0, 0, 0); PSTG(0, 1, 0); PSTG(1, 0, 1);
  GATE6;
  SBAR;
  SCHED0;
  PFRAG(0, 0, afA, bfA);
  LGKM0;
  SCHED0;

  int NI = Kd >> 7;
  for (int it = 0; it < NI - 1; ++it) {
    int t = 2 * it;
    PPH(afA, bfA, 0, 1, afB, bfB, PSTG(1, 1, t + 1), GATE3);
    PPH(afB, bfB, 1, 0, afA, bfA, PSTG(0, 0, t + 2), GATE3);
    PPH(afA, bfA, 1, 1, afB, bfB, PSTG(0, 1, t + 2), GATE3);
    PPH(afB, bfB, 0, 0, afA, bfA, PSTG(1, 0, t + 3), GATE3);
  }
  {
    int t = 2 * (NI - 1);
    PPH(afA, bfA, 0, 1, afB, bfB, PSTG(1, 1, t + 1), GATE3);
    PPH(afB, bfB, 1, 0, afA, bfA, NOSTG, GATE0);
    PPH(afA, bfA, 1, 1, afB, bfB, NOSTG, NOGATE);
    PMFMA(afB, bfB);
  }

  int crow = (int)m0 + wm + (lanev << 2);
  int ccol = (int)n0 + wn + laneh;

  if constexpr (EPI == 0) {
    u16* C = (u16*)Cout;
#pragma unroll
    for (int mi = 0; mi < 4; ++mi)
#pragma unroll
      for (int r = 0; r < 4; ++r) {
        size_t row = (size_t)(crow + mi * 16 + r);
#pragma unroll
        for (int ni = 0; ni < 4; ++ni)
          C[row * N + ccol + ni * 16] = f2bf(acc[mi][ni][r] + aux[ccol + ni * 16]);
      }
  } else {
    float* C = (float*)Cout;
#pragma unroll
    for (int mi = 0; mi < 4; ++mi)
#pragma unroll
      for (int r = 0; r < 4; ++r) {
        int row = crow + mi * 16 + r;
        float inv = 1.0f / aux[row];
        size_t rbase = (size_t)row * N + ccol;
#pragma unroll
        for (int ni = 0; ni < 4; ++ni)
          C[rbase + ni * 16] = xres[rbase + ni * 16] + acc[mi][ni][r] * inv;
      }
  }
}

// ---------------- NT GEMM 128^2 (K-proj, V-proj^T) --------------------------
template <int EPI>
__global__ __launch_bounds__(256) void gemm_nt(
    const u16* __restrict__ A, const u16* __restrict__ Bt,
    void* __restrict__ Cout, int M, int N, int K,
    const float* __restrict__ aux1) {
  constexpr int BK = 64;
  __shared__ u16 As[128 * BK];
  __shared__ u16 Bs[128 * BK];

  int nwg = gridDim.x;
  int bid = blockIdx.x;
  int swz = ((nwg & 7) == 0) ? ((bid & 7) * (nwg >> 3) + (bid >> 3)) : bid;
  int nbm = M >> 7;
  int bm = swz % nbm;
  int bn = swz / nbm;

  int tid = threadIdx.x;
  int lane = tid & 63;
  int wave = tid >> 6;
  int wm = (wave >> 1) << 6;
  int wn = (wave & 1) << 6;
  size_t m0 = (size_t)bm << 7;
  size_t n0 = (size_t)bn << 7;

  int srow = tid >> 3;
  int scol = (tid & 7) << 3;

  f32x4 acc[4][4] = {};

  const u16* Ag = A + (m0 + srow) * K + scol;
  const u16* Bg = Bt + (n0 + srow) * K + scol;
  u16* Asw = &As[wave * 512];
  u16* Bsw = &Bs[wave * 512];

  int laneh = lane & 15;
  int lanev = lane >> 4;

  for (int k0 = 0; k0 < K; k0 += BK) {
#pragma unroll
    for (int i = 0; i < 4; ++i) {
      gload_lds16(Ag + (size_t)i * 32 * K + k0, Asw + i * 2048);
      gload_lds16(Bg + (size_t)i * 32 * K + k0, Bsw + i * 2048);
    }
    __syncthreads();
#pragma unroll
    for (int kk = 0; kk < 2; ++kk) {
      s16x8 af[4], bfr[4];
#pragma unroll
      for (int i = 0; i < 4; ++i) {
        af[i]  = *(const s16x8*)&As[(wm + i * 16 + laneh) * BK + kk * 32 + lanev * 8];
        bfr[i] = *(const s16x8*)&Bs[(wn + i * 16 + laneh) * BK + kk * 32 + lanev * 8];
      }
#pragma unroll
      for (int mi = 0; mi < 4; ++mi)
#pragma unroll
        for (int ni = 0; ni < 4; ++ni)
          acc[mi][ni] = __builtin_amdgcn_mfma_f32_16x16x32_bf16(
              af[mi], bfr[ni], acc[mi][ni], 0, 0, 0);
    }
    __syncthreads();
  }

  int crow = (int)m0 + wm + (lanev << 2);
  int ccol = (int)n0 + wn + laneh;

  if constexpr (EPI == 0) {
    u16* C = (u16*)Cout;
#pragma unroll
    for (int mi = 0; mi < 4; ++mi)
#pragma unroll
      for (int r = 0; r < 4; ++r) {
        size_t row = (size_t)(crow + mi * 16 + r);
#pragma unroll
        for (int ni = 0; ni < 4; ++ni)
          C[row * N + ccol + ni * 16] = f2bf(acc[mi][ni][r] + aux1[ccol + ni * 16]);
      }
  } else {
    u16* C = (u16*)Cout;  // [N][M]
#pragma unroll
    for (int ni = 0; ni < 4; ++ni) {
      float b = aux1[ccol + ni * 16];
#pragma unroll
      for (int mi = 0; mi < 4; ++mi) {
        s16x4 v;
#pragma unroll
        for (int r = 0; r < 4; ++r) v[r] = (short)f2bf(acc[mi][ni][r] + b);
        *(s16x4*)&C[(size_t)(ccol + ni * 16) * M + crow + mi * 16] = v;
      }
    }
  }
}

extern "C" void kernel_launch(void* const* d_in, const int* in_sizes, int n_in,
                              void* d_out, int out_size, void* d_ws, size_t ws_size,
                              hipStream_t stream) {
  const float* x  = (const float*)d_in[0];
  const float* mb = (const float*)d_in[1];
  const float* Wq = (const float*)d_in[2];
  const float* bq = (const float*)d_in[3];
  const float* Wk = (const float*)d_in[4];
  const float* bk = (const float*)d_in[5];
  const float* Wv = (const float*)d_in[6];
  const float* bv = (const float*)d_in[7];
  float* out = (float*)d_out;

  const int B = 8192, H = 1024, Mm = 4096;

  char* ws = (char*)d_ws;
  u16* xb  = (u16*)ws; ws += (size_t)B * H * 2;
  u16* mbb = (u16*)ws; ws += (size_t)Mm * H * 2;
  u16* Wqt = (u16*)ws; ws += (size_t)H * H * 2;
  u16* Wkt = (u16*)ws; ws += (size_t)H * H * 2;
  u16* Wvt = (u16*)ws; ws += (size_t)H * H * 2;
  u16* Q   = (u16*)ws; ws += (size_t)B * H * 2;
  u16* Kp  = (u16*)ws; ws += (size_t)Mm * H * 2;
  u16* Vt  = (u16*)ws; ws += (size_t)H * Mm * 2;
  u16* S   = (u16*)ws; ws += (size_t)B * Mm * 2;
  float* sums = (float*)ws;

  hipMemsetAsync(sums, 0, (size_t)B * sizeof(float), stream);

  cast_bf16_kernel<<<2048, 256, 0, stream>>>(x, xb, B * H / 8);
  cast_bf16_kernel<<<1024, 256, 0, stream>>>(mb, mbb, Mm * H / 8);
  tcast_kernel<<<(H / 32) * (H / 32), 256, 0, stream>>>(Wq, Wqt, H, H);
  tcast_kernel<<<(H / 32) * (H / 32), 256, 0, stream>>>(Wk, Wkt, H, H);
  tcast_kernel<<<(H / 32) * (H / 32), 256, 0, stream>>>(Wv, Wvt, H, H);

  gemm_pipe<0><<<(B / 256) * (H / 128), 512, 0, stream>>>(
      xb, Wqt, Q, bq, nullptr, B, H, H);
  gemm_nt<0><<<(Mm / 128) * (H / 128), 256, 0, stream>>>(mbb, Wkt, Kp, Mm, H, H, bk);
  gemm_nt<1><<<(Mm / 128) * (H / 128), 256, 0, stream>>>(mbb, Wvt, Vt, Mm, H, H, bv);

  gemm_qkt_exp<<<(B / 256) * (Mm / 256), 512, 0, stream>>>(Q, Kp, S, sums, B, Mm, H);

  gemm_pipe<3><<<(B / 256) * (H / 128), 512, 0, stream>>>(
      S, Vt, out, sums, x, B, H, Mm);
}

// Round 6
// 242.362 us; speedup vs baseline: 1.2712x; 1.0030x over previous
//
#include <hip/hip_runtime.h>
#include <stdint.h>

typedef unsigned short u16;
using f32x4 = __attribute__((ext_vector_type(4))) float;
using s16x8 = __attribute__((ext_vector_type(8))) short;
using s16x4 = __attribute__((ext_vector_type(4))) short;

__device__ __forceinline__ float bf2f(u16 u) {
  union { uint32_t u; float f; } v; v.u = ((uint32_t)u) << 16; return v.f;
}
__device__ __forceinline__ u16 f2bf(float f) {
  union { float f; uint32_t u; } v; v.f = f;
  uint32_t u = v.u;
  return (u16)((u + 0x7fffu + ((u >> 16) & 1u)) >> 16);
}

__device__ __forceinline__ void gload_lds16(const void* g, void* l) {
  __builtin_amdgcn_global_load_lds(
      (const __attribute__((address_space(1))) void*)g,
      (__attribute__((address_space(3))) void*)l, 16, 0, 0);
}

// opaque ds_read: no memory clobber -> waitcnt pass attaches nothing to it
#define DSRO(dst, base, offbytes) \
  asm volatile("ds_read_b128 %0, %1 offset:%2" : "=v"(dst) : "v"(base), "i"(offbytes))

// ---------------- cast f32 -> bf16 (vectorized, grid-stride) ----------------
__global__ __launch_bounds__(256) void cast_bf16_kernel(
    const float* __restrict__ in, u16* __restrict__ out, int n8) {
  int idx = blockIdx.x * blockDim.x + threadIdx.x;
  int stride = gridDim.x * blockDim.x;
  for (int i = idx; i < n8; i += stride) {
    const float4* p = (const float4*)(in + (size_t)i * 8);
    float4 a = p[0], b = p[1];
    s16x8 o;
    o[0] = (short)f2bf(a.x); o[1] = (short)f2bf(a.y);
    o[2] = (short)f2bf(a.z); o[3] = (short)f2bf(a.w);
    o[4] = (short)f2bf(b.x); o[5] = (short)f2bf(b.y);
    o[6] = (short)f2bf(b.z); o[7] = (short)f2bf(b.w);
    *(s16x8*)(out + (size_t)i * 8) = o;
  }
}

// ------------- transpose-cast: W[K][N] f32 -> Wt[N][K] bf16 -----------------
__global__ __launch_bounds__(256) void tcast_kernel(
    const float* __restrict__ W, u16* __restrict__ Wt, int Kd, int Nd) {
  __shared__ u16 tile[32][33];
  int nbx = Nd / 32;
  int bx = blockIdx.x % nbx;
  int by = blockIdx.x / nbx;
  int tr = threadIdx.x >> 5;
  int tc = threadIdx.x & 31;
#pragma unroll
  for (int i = 0; i < 4; ++i)
    tile[tr + i * 8][tc] = f2bf(W[(size_t)(by * 32 + tr + i * 8) * Nd + bx * 32 + tc]);
  __syncthreads();
#pragma unroll
  for (int i = 0; i < 4; ++i)
    Wt[(size_t)(bx * 32 + tr + i * 8) * Kd + by * 32 + tc] = tile[tc][tr + i * 8];
}

// ============================ sync / gate macros ============================
#define GATE8 asm volatile("s_waitcnt vmcnt(8)" ::: "memory")
#define GATE6 asm volatile("s_waitcnt vmcnt(6)" ::: "memory")
#define GATE3 asm volatile("s_waitcnt vmcnt(3)" ::: "memory")
#define GATE2 asm volatile("s_waitcnt vmcnt(2)" ::: "memory")
#define GATE0 asm volatile("s_waitcnt vmcnt(0)" ::: "memory")
#define NOGATE (void)0
#define NOSTG (void)0
#define LGKM0 asm volatile("s_waitcnt lgkmcnt(0)" ::: "memory")
#define SBARA asm volatile("s_barrier" ::: "memory")  // opaque: no vmcnt(0) drain
#define SCHED0 __builtin_amdgcn_sched_barrier(0)

// ======================= 8-phase 256x256 QK^T kernel ========================
// C[M][N] = exp((A@Bt^T)/32) bf16; also atomicAdd per-row sums of C.

#define STG_A(buf, h, kt) do { \
    const u16* s_ = Asrc + (size_t)(kt) * 64 + (h) * 32; \
    gload_lds16(s_, &As[buf][h][wave * 512]); \
    gload_lds16(s_ + srow128, &As[buf][h][wave * 512 + 4096]); \
  } while (0)

#define STG_B(buf, h, kt) do { \
    const u16* s_ = Bsrc + (size_t)(kt) * 64 + (h) * 32; \
    gload_lds16(s_, &Bs[buf][h][wave * 512]); \
    gload_lds16(s_ + srow128, &Bs[buf][h][wave * 512 + 4096]); \
  } while (0)

#define DS_FRAGS(buf, kk, mh) do { \
    DSRO(af[0], aB[buf][kk], (mh) * 4096 + 0); \
    DSRO(af[1], aB[buf][kk], (mh) * 4096 + 1024); \
    DSRO(af[2], aB[buf][kk], (mh) * 4096 + 2048); \
    DSRO(af[3], aB[buf][kk], (mh) * 4096 + 3072); \
    if ((mh) == 0) { \
      DSRO(bf[0], bB[buf][kk], 0); \
      DSRO(bf[1], bB[buf][kk], 1024); \
      DSRO(bf[2], bB[buf][kk], 2048); \
      DSRO(bf[3], bB[buf][kk], 3072); \
    } \
  } while (0)

// one barrier per phase; counted gate before it; reads drained before MFMA
#define PHASE(buf, kk, mh, STAGE, GATE) do { \
    DS_FRAGS(buf, kk, mh); \
    STAGE; \
    LGKM0; \
    SCHED0; \
    __builtin_amdgcn_s_setprio(1); \
    _Pragma("unroll") \
    for (int i2 = 0; i2 < 4; ++i2) \
      _Pragma("unroll") \
      for (int j2 = 0; j2 < 4; ++j2) \
        acc[(mh) * 4 + i2][j2] = __builtin_amdgcn_mfma_f32_16x16x32_bf16( \
            af[i2], bf[j2], acc[(mh) * 4 + i2][j2], 0, 0, 0); \
    __builtin_amdgcn_s_setprio(0); \
    SCHED0; \
    GATE; \
    SBARA; \
  } while (0)

__global__ __launch_bounds__(512, 2) void gemm_qkt_exp(
    const u16* __restrict__ A, const u16* __restrict__ Bt, u16* __restrict__ C,
    float* __restrict__ sums, int M, int N, int Kd) {
  __shared__ u16 As[2][2][256 * 32];
  __shared__ u16 Bs[2][2][256 * 32];

  int nwg = gridDim.x;
  int bid = blockIdx.x;
  int swz = ((nwg & 7) == 0) ? ((bid & 7) * (nwg >> 3) + (bid >> 3)) : bid;
  int nbm = M >> 8;
  int bm = swz % nbm;
  int bn = swz / nbm;
  size_t m0 = (size_t)bm << 8;
  size_t n0 = (size_t)bn << 8;

  int tid = threadIdx.x;
  int lane = tid & 63;
  int wave = tid >> 6;
  int wm = (wave >> 2) * 128;
  int wn = (wave & 3) * 64;
  int laneh = lane & 15;
  int lanev = lane >> 4;
  int aswz = ((lanev ^ ((laneh >> 1) & 3)) << 3);

  int prow = tid >> 2;
  int lslot = (tid & 3) ^ ((tid >> 3) & 3);
  const u16* Asrc = A + (m0 + prow) * Kd + lslot * 8;
  const u16* Bsrc = Bt + (n0 + prow) * Kd + lslot * 8;
  size_t srow128 = (size_t)128 * Kd;

  uint32_t aB[2][2], bB[2][2];
#pragma unroll
  for (int b = 0; b < 2; ++b)
#pragma unroll
    for (int k2 = 0; k2 < 2; ++k2) {
      aB[b][k2] = (uint32_t)(uintptr_t)&As[b][k2][(wm + laneh) * 32 + aswz];
      bB[b][k2] = (uint32_t)(uintptr_t)&Bs[b][k2][(wn + laneh) * 32 + aswz];
    }

  f32x4 acc[8][4] = {};
  s16x8 af[4], bf[4];

  // prologue: 6 regions (12 loads); oldest 4 (=A00,B00) must land
  STG_A(0, 0, 0); STG_B(0, 0, 0);
  STG_A(0, 1, 0); STG_B(0, 1, 0);
  STG_A(1, 0, 1); STG_B(1, 0, 1);
  GATE8;
  SBARA;

  int NI = Kd >> 7;
  for (int it = 0; it < NI - 1; ++it) {
    int t = 2 * it;
    PHASE(0, 0, 0, STG_A(1, 1, t + 1), GATE6);
    PHASE(0, 0, 1, STG_B(1, 1, t + 1), GATE6);
    PHASE(0, 1, 0, STG_A(0, 0, t + 2), GATE6);
    PHASE(0, 1, 1, STG_B(0, 0, t + 2), GATE6);
    PHASE(1, 0, 0, STG_A(0, 1, t + 2), GATE6);
    PHASE(1, 0, 1, STG_B(0, 1, t + 2), GATE6);
    PHASE(1, 1, 0, STG_A(1, 0, t + 3), GATE6);
    PHASE(1, 1, 1, STG_B(1, 0, t + 3), GATE6);
  }
  {  // drain: gates 6,6,-,2,-,0,-,-
    int t = 2 * (NI - 1);
    PHASE(0, 0, 0, STG_A(1, 1, t + 1), GATE6);
    PHASE(0, 0, 1, STG_B(1, 1, t + 1), GATE6);
    PHASE(0, 1, 0, NOSTG, NOGATE);
    PHASE(0, 1, 1, NOSTG, GATE2);
    PHASE(1, 0, 0, NOSTG, NOGATE);
    PHASE(1, 0, 1, NOSTG, GATE0);
    PHASE(1, 1, 0, NOSTG, NOGATE);
    PHASE(1, 1, 1, NOSTG, NOGATE);
  }

  // epilogue: exp -> bf16 store via per-wave LDS bounce + per-row atomic sums
  u16* epw = ((u16*)As) + wave * 1152;  // [16][72] u16
#pragma unroll
  for (int a = 0; a < 8; ++a) {
#pragma unroll
    for (int r = 0; r < 4; ++r)
#pragma unroll
      for (int j = 0; j < 4; ++j)
        epw[(lanev * 4 + r) * 72 + laneh + j * 16] =
            f2bf(__expf(acc[a][j][r] * 0.03125f));
    int rowoff = ((a >> 2) * 64) + ((a & 3) * 16);
#pragma unroll
    for (int p = 0; p < 2; ++p) {
      s16x8 v = *(const s16x8*)&epw[((lane >> 3) + 8 * p) * 72 + (lane & 7) * 8];
      size_t grow = m0 + wm + rowoff + (lane >> 3) + 8 * p;
      *(s16x8*)&C[grow * N + n0 + wn + (lane & 7) * 8] = v;
      float s = 0.f;
#pragma unroll
      for (int j = 0; j < 8; ++j) s += bf2f((u16)v[j]);
      s += __shfl_xor(s, 1, 64);
      s += __shfl_xor(s, 2, 64);
      s += __shfl_xor(s, 4, 64);
      if ((lane & 7) == 0) atomicAdd(&sums[grow], s);
    }
  }
}

// ============== 4-phase 256x128 pipelined GEMM (Q-proj / PV) ================
// EPI 0: C bf16 = acc + bias(aux).   EPI 3: C f32 = xres + acc / sums[row].

#define PSTG(buf, h, kt) do { \
    const u16* sa_ = Asrc + (size_t)(kt) * 64 + (h) * 32; \
    gload_lds16(sa_, &As[buf][h][wave * 512]); \
    gload_lds16(sa_ + srow128, &As[buf][h][wave * 512 + 4096]); \
    const u16* sb_ = Bsrc + (size_t)(kt) * 64 + (h) * 32; \
    gload_lds16(sb_, &Bs[buf][h][wave * 512]); \
  } while (0)

#define PPH(buf, kk, STAGE, GATE) do { \
    DSRO(af[0], pA[buf][kk], 0); \
    DSRO(af[1], pA[buf][kk], 1024); \
    DSRO(af[2], pA[buf][kk], 2048); \
    DSRO(af[3], pA[buf][kk], 3072); \
    DSRO(bf[0], pB[buf][kk], 0); \
    DSRO(bf[1], pB[buf][kk], 1024); \
    DSRO(bf[2], pB[buf][kk], 2048); \
    DSRO(bf[3], pB[buf][kk], 3072); \
    STAGE; \
    LGKM0; \
    SCHED0; \
    __builtin_amdgcn_s_setprio(1); \
    _Pragma("unroll") \
    for (int i2 = 0; i2 < 4; ++i2) \
      _Pragma("unroll") \
      for (int j2 = 0; j2 < 4; ++j2) \
        acc[i2][j2] = __builtin_amdgcn_mfma_f32_16x16x32_bf16( \
            af[i2], bf[j2], acc[i2][j2], 0, 0, 0); \
    __builtin_amdgcn_s_setprio(0); \
    SCHED0; \
    GATE; \
    SBARA; \
  } while (0)

template <int EPI>
__global__ __launch_bounds__(512, 2) void gemm_pipe(
    const u16* __restrict__ A, const u16* __restrict__ Bt,
    void* __restrict__ Cout, const float* __restrict__ aux,
    const float* __restrict__ xres, int M, int N, int Kd) {
  __shared__ u16 As[2][2][256 * 32];  // 64 KiB
  __shared__ u16 Bs[2][2][128 * 32];  // 32 KiB

  int bid = blockIdx.x;
  int bm = (bid & 7) * 4 + ((bid >> 3) & 3);
  int bn = bid >> 5;
  size_t m0 = (size_t)bm << 8;
  size_t n0 = (size_t)bn << 7;

  int tid = threadIdx.x;
  int lane = tid & 63;
  int wave = tid >> 6;
  int wm = (wave >> 1) * 64;
  int wn = (wave & 1) * 64;
  int laneh = lane & 15;
  int lanev = lane >> 4;
  int aswz = ((lanev ^ ((laneh >> 1) & 3)) << 3);

  int prow = tid >> 2;
  int lslot = (tid & 3) ^ ((tid >> 3) & 3);
  const u16* Asrc = A + (m0 + prow) * Kd + lslot * 8;
  const u16* Bsrc = Bt + (n0 + prow) * Kd + lslot * 8;
  size_t srow128 = (size_t)128 * Kd;

  uint32_t pA[2][2], pB[2][2];
#pragma unroll
  for (int b = 0; b < 2; ++b)
#pragma unroll
    for (int k2 = 0; k2 < 2; ++k2) {
      pA[b][k2] = (uint32_t)(uintptr_t)&As[b][k2][(wm + laneh) * 32 + aswz];
      pB[b][k2] = (uint32_t)(uintptr_t)&Bs[b][k2][(wn + laneh) * 32 + aswz];
    }

  f32x4 acc[4][4] = {};
  s16x8 af[4], bf[4];

  PSTG(0, 0, 0); PSTG(0, 1, 0); PSTG(1, 0, 1);
  GATE6;
  SBARA;

  int NI = Kd >> 7;
  for (int it = 0; it < NI - 1; ++it) {
    int t = 2 * it;
    PPH(0, 0, PSTG(1, 1, t + 1), GATE6);
    PPH(0, 1, PSTG(0, 0, t + 2), GATE6);
    PPH(1, 0, PSTG(0, 1, t + 2), GATE6);
    PPH(1, 1, PSTG(1, 0, t + 3), GATE6);
  }
  {
    int t = 2 * (NI - 1);
    PPH(0, 0, PSTG(1, 1, t + 1), GATE6);
    PPH(0, 1, NOSTG, GATE3);
    PPH(1, 0, NOSTG, GATE0);
    PPH(1, 1, NOSTG, NOGATE);
  }

  int crow = (int)m0 + wm + (lanev << 2);
  int ccol = (int)n0 + wn + laneh;

  if constexpr (EPI == 0) {
    u16* C = (u16*)Cout;
#pragma unroll
    for (int mi = 0; mi < 4; ++mi)
#pragma unroll
      for (int r = 0; r < 4; ++r) {
        size_t row = (size_t)(crow + mi * 16 + r);
#pragma unroll
        for (int ni = 0; ni < 4; ++ni)
          C[row * N + ccol + ni * 16] = f2bf(acc[mi][ni][r] + aux[ccol + ni * 16]);
      }
  } else {
    float* C = (float*)Cout;
#pragma unroll
    for (int mi = 0; mi < 4; ++mi)
#pragma unroll
      for (int r = 0; r < 4; ++r) {
        int row = crow + mi * 16 + r;
        float inv = 1.0f / aux[row];
        size_t rbase = (size_t)row * N + ccol;
#pragma unroll
        for (int ni = 0; ni < 4; ++ni)
          C[rbase + ni * 16] = xres[rbase + ni * 16] + acc[mi][ni][r] * inv;
      }
  }
}

// ---------------- NT GEMM 128^2 (K-proj, V-proj^T) --------------------------
template <int EPI>
__global__ __launch_bounds__(256) void gemm_nt(
    const u16* __restrict__ A, const u16* __restrict__ Bt,
    void* __restrict__ Cout, int M, int N, int K,
    const float* __restrict__ aux1) {
  constexpr int BK = 64;
  __shared__ u16 As[128 * BK];
  __shared__ u16 Bs[128 * BK];

  int nwg = gridDim.x;
  int bid = blockIdx.x;
  int swz = ((nwg & 7) == 0) ? ((bid & 7) * (nwg >> 3) + (bid >> 3)) : bid;
  int nbm = M >> 7;
  int bm = swz % nbm;
  int bn = swz / nbm;

  int tid = threadIdx.x;
  int lane = tid & 63;
  int wave = tid >> 6;
  int wm = (wave >> 1) << 6;
  int wn = (wave & 1) << 6;
  size_t m0 = (size_t)bm << 7;
  size_t n0 = (size_t)bn << 7;

  int srow = tid >> 3;
  int scol = (tid & 7) << 3;

  f32x4 acc[4][4] = {};

  const u16* Ag = A + (m0 + srow) * K + scol;
  const u16* Bg = Bt + (n0 + srow) * K + scol;
  u16* Asw = &As[wave * 512];
  u16* Bsw = &Bs[wave * 512];

  int laneh = lane & 15;
  int lanev = lane >> 4;

  for (int k0 = 0; k0 < K; k0 += BK) {
#pragma unroll
    for (int i = 0; i < 4; ++i) {
      gload_lds16(Ag + (size_t)i * 32 * K + k0, Asw + i * 2048);
      gload_lds16(Bg + (size_t)i * 32 * K + k0, Bsw + i * 2048);
    }
    __syncthreads();
#pragma unroll
    for (int kk = 0; kk < 2; ++kk) {
      s16x8 af[4], bfr[4];
#pragma unroll
      for (int i = 0; i < 4; ++i) {
        af[i]  = *(const s16x8*)&As[(wm + i * 16 + laneh) * BK + kk * 32 + lanev * 8];
        bfr[i] = *(const s16x8*)&Bs[(wn + i * 16 + laneh) * BK + kk * 32 + lanev * 8];
      }
#pragma unroll
      for (int mi = 0; mi < 4; ++mi)
#pragma unroll
        for (int ni = 0; ni < 4; ++ni)
          acc[mi][ni] = __builtin_amdgcn_mfma_f32_16x16x32_bf16(
              af[mi], bfr[ni], acc[mi][ni], 0, 0, 0);
    }
    __syncthreads();
  }

  int crow = (int)m0 + wm + (lanev << 2);
  int ccol = (int)n0 + wn + laneh;

  if constexpr (EPI == 0) {
    u16* C = (u16*)Cout;
#pragma unroll
    for (int mi = 0; mi < 4; ++mi)
#pragma unroll
      for (int r = 0; r < 4; ++r) {
        size_t row = (size_t)(crow + mi * 16 + r);
#pragma unroll
        for (int ni = 0; ni < 4; ++ni)
          C[row * N + ccol + ni * 16] = f2bf(acc[mi][ni][r] + aux1[ccol + ni * 16]);
      }
  } else {
    u16* C = (u16*)Cout;  // [N][M]
#pragma unroll
    for (int ni = 0; ni < 4; ++ni) {
      float b = aux1[ccol + ni * 16];
#pragma unroll
      for (int mi = 0; mi < 4; ++mi) {
        s16x4 v;
#pragma unroll
        for (int r = 0; r < 4; ++r) v[r] = (short)f2bf(acc[mi][ni][r] + b);
        *(s16x4*)&C[(size_t)(ccol + ni * 16) * M + crow + mi * 16] = v;
      }
    }
  }
}

extern "C" void kernel_launch(void* const* d_in, const int* in_sizes, int n_in,
                              void* d_out, int out_size, void* d_ws, size_t ws_size,
                              hipStream_t stream) {
  const float* x  = (const float*)d_in[0];
  const float* mb = (const float*)d_in[1];
  const float* Wq = (const float*)d_in[2];
  const float* bq = (const float*)d_in[3];
  const float* Wk = (const float*)d_in[4];
  const float* bk = (const float*)d_in[5];
  const float* Wv = (const float*)d_in[6];
  const float* bv = (const float*)d_in[7];
  float* out = (float*)d_out;

  const int B = 8192, H = 1024, Mm = 4096;

  char* ws = (char*)d_ws;
  u16* xb  = (u16*)ws; ws += (size_t)B * H * 2;
  u16* mbb = (u16*)ws; ws += (size_t)Mm * H * 2;
  u16* Wqt = (u16*)ws; ws += (size_t)H * H * 2;
  u16* Wkt = (u16*)ws; ws += (size_t)H * H * 2;
  u16* Wvt = (u16*)ws; ws += (size_t)H * H * 2;
  u16* Q   = (u16*)ws; ws += (size_t)B * H * 2;
  u16* Kp  = (u16*)ws; ws += (size_t)Mm * H * 2;
  u16* Vt  = (u16*)ws; ws += (size_t)H * Mm * 2;
  u16* S   = (u16*)ws; ws += (size_t)B * Mm * 2;
  float* sums = (float*)ws;

  hipMemsetAsync(sums, 0, (size_t)B * sizeof(float), stream);

  cast_bf16_kernel<<<2048, 256, 0, stream>>>(x, xb, B * H / 8);
  cast_bf16_kernel<<<1024, 256, 0, stream>>>(mb, mbb, Mm * H / 8);
  tcast_kernel<<<(H / 32) * (H / 32), 256, 0, stream>>>(Wq, Wqt, H, H);
  tcast_kernel<<<(H / 32) * (H / 32), 256, 0, stream>>>(Wk, Wkt, H, H);
  tcast_kernel<<<(H / 32) * (H / 32), 256, 0, stream>>>(Wv, Wvt, H, H);

  gemm_pipe<0><<<(B / 256) * (H / 128), 512, 0, stream>>>(
      xb, Wqt, Q, bq, nullptr, B, H, H);
  gemm_nt<0><<<(Mm / 128) * (H / 128), 256, 0, stream>>>(mbb, Wkt, Kp, Mm, H, H, bk);
  gemm_nt<1><<<(Mm / 128) * (H / 128), 256, 0, stream>>>(mbb, Wvt, Vt, Mm, H, H, bv);

  gemm_qkt_exp<<<(B / 256) * (Mm / 256), 512, 0, stream>>>(Q, Kp, S, sums, B, Mm, H);

  gemm_pipe<3><<<(B / 256) * (H / 128), 512, 0, stream>>>(
      S, Vt, out, sums, x, B, H, Mm);
}

// Round 7
// 241.983 us; speedup vs baseline: 1.2732x; 1.0016x over previous
//
#include <hip/hip_runtime.h>
#include <stdint.h>

typedef unsigned short u16;
using f32x4 = __attribute__((ext_vector_type(4))) float;
using s16x8 = __attribute__((ext_vector_type(8))) short;
using s16x4 = __attribute__((ext_vector_type(4))) short;

__device__ __forceinline__ float bf2f(u16 u) {
  union { uint32_t u; float f; } v; v.u = ((uint32_t)u) << 16; return v.f;
}
__device__ __forceinline__ u16 f2bf(float f) {
  union { float f; uint32_t u; } v; v.f = f;
  uint32_t u = v.u;
  return (u16)((u + 0x7fffu + ((u >> 16) & 1u)) >> 16);
}

__device__ __forceinline__ void gload_lds16(const void* g, void* l) {
  __builtin_amdgcn_global_load_lds(
      (const __attribute__((address_space(1))) void*)g,
      (__attribute__((address_space(3))) void*)l, 16, 0, 0);
}

#define DSRO(dst, base, offbytes) \
  asm volatile("ds_read_b128 %0, %1 offset:%2" : "=v"(dst) : "v"(base), "i"(offbytes))

// ---------------- cast f32 -> bf16 (vectorized, grid-stride) ----------------
__global__ __launch_bounds__(256) void cast_bf16_kernel(
    const float* __restrict__ in, u16* __restrict__ out, int n8) {
  int idx = blockIdx.x * blockDim.x + threadIdx.x;
  int stride = gridDim.x * blockDim.x;
  for (int i = idx; i < n8; i += stride) {
    const float4* p = (const float4*)(in + (size_t)i * 8);
    float4 a = p[0], b = p[1];
    s16x8 o;
    o[0] = (short)f2bf(a.x); o[1] = (short)f2bf(a.y);
    o[2] = (short)f2bf(a.z); o[3] = (short)f2bf(a.w);
    o[4] = (short)f2bf(b.x); o[5] = (short)f2bf(b.y);
    o[6] = (short)f2bf(b.z); o[7] = (short)f2bf(b.w);
    *(s16x8*)(out + (size_t)i * 8) = o;
  }
}

// ------------- transpose-cast: W[K][N] f32 -> Wt[N][K] bf16 -----------------
__global__ __launch_bounds__(256) void tcast_kernel(
    const float* __restrict__ W, u16* __restrict__ Wt, int Kd, int Nd) {
  __shared__ u16 tile[32][33];
  int nbx = Nd / 32;
  int bx = blockIdx.x % nbx;
  int by = blockIdx.x / nbx;
  int tr = threadIdx.x >> 5;
  int tc = threadIdx.x & 31;
#pragma unroll
  for (int i = 0; i < 4; ++i)
    tile[tr + i * 8][tc] = f2bf(W[(size_t)(by * 32 + tr + i * 8) * Nd + bx * 32 + tc]);
  __syncthreads();
#pragma unroll
  for (int i = 0; i < 4; ++i)
    Wt[(size_t)(bx * 32 + tr + i * 8) * Kd + by * 32 + tc] = tile[tc][tr + i * 8];
}

// ============================ sync / gate macros ============================
#define GATE4 asm volatile("s_waitcnt vmcnt(4)" ::: "memory")
#define GATE2 asm volatile("s_waitcnt vmcnt(2)" ::: "memory")
#define GATE0 asm volatile("s_waitcnt vmcnt(0)" ::: "memory")
#define LGKM0 asm volatile("s_waitcnt lgkmcnt(0)" ::: "memory")
#define SBARA asm volatile("s_barrier" ::: "memory")
#define SCHED0 __builtin_amdgcn_sched_barrier(0)
#define NOSTG (void)0
#define NOTAIL (void)0
#define TAIL_G2 do { GATE2; SBARA; } while (0)
#define TAIL_G0 do { GATE0; SBARA; } while (0)
#define TAIL_B  do { SBARA; } while (0)

// ======================= 8-phase 256x256 QK^T kernel ========================
// C[M][N] = exp((A@Bt^T)/32) bf16; also atomicAdd per-row sums of C.
// Barriers+gates only at ODD phase ends (WAR/RAW ledger verified): waves
// free-run within 2-phase windows so per-wave lgkm staggers overlap LDS+MFMA.

#define STG_A(buf, h, kt) do { \
    const u16* s_ = Asrc + (size_t)(kt) * 64 + (h) * 32; \
    gload_lds16(s_, &As[buf][h][wave * 512]); \
    gload_lds16(s_ + srow128, &As[buf][h][wave * 512 + 4096]); \
  } while (0)

#define STG_B(buf, h, kt) do { \
    const u16* s_ = Bsrc + (size_t)(kt) * 64 + (h) * 32; \
    gload_lds16(s_, &Bs[buf][h][wave * 512]); \
    gload_lds16(s_ + srow128, &Bs[buf][h][wave * 512 + 4096]); \
  } while (0)

#define DS_FRAGS(buf, kk, mh) do { \
    DSRO(af[0], aB[buf][kk], (mh) * 4096 + 0); \
    DSRO(af[1], aB[buf][kk], (mh) * 4096 + 1024); \
    DSRO(af[2], aB[buf][kk], (mh) * 4096 + 2048); \
    DSRO(af[3], aB[buf][kk], (mh) * 4096 + 3072); \
    if ((mh) == 0) { \
      DSRO(bf[0], bB[buf][kk], 0); \
      DSRO(bf[1], bB[buf][kk], 1024); \
      DSRO(bf[2], bB[buf][kk], 2048); \
      DSRO(bf[3], bB[buf][kk], 3072); \
    } \
  } while (0)

#define QPH(buf, kk, mh, STAGE, TAIL) do { \
    DS_FRAGS(buf, kk, mh); \
    STAGE; \
    LGKM0; \
    SCHED0; \
    __builtin_amdgcn_s_setprio(1); \
    _Pragma("unroll") \
    for (int i2 = 0; i2 < 4; ++i2) \
      _Pragma("unroll") \
      for (int j2 = 0; j2 < 4; ++j2) \
        acc[(mh) * 4 + i2][j2] = __builtin_amdgcn_mfma_f32_16x16x32_bf16( \
            af[i2], bf[j2], acc[(mh) * 4 + i2][j2], 0, 0, 0); \
    __builtin_amdgcn_s_setprio(0); \
    SCHED0; \
    TAIL; \
  } while (0)

__global__ __launch_bounds__(512, 2) void gemm_qkt_exp(
    const u16* __restrict__ A, const u16* __restrict__ Bt, u16* __restrict__ C,
    float* __restrict__ sums, int M, int N, int Kd) {
  __shared__ u16 As[2][2][256 * 32];
  __shared__ u16 Bs[2][2][256 * 32];

  int nwg = gridDim.x;
  int bid = blockIdx.x;
  int swz = ((nwg & 7) == 0) ? ((bid & 7) * (nwg >> 3) + (bid >> 3)) : bid;
  int nbm = M >> 8;
  int bm = swz % nbm;
  int bn = swz / nbm;
  size_t m0 = (size_t)bm << 8;
  size_t n0 = (size_t)bn << 8;

  int tid = threadIdx.x;
  int lane = tid & 63;
  int wave = tid >> 6;
  int wm = (wave >> 2) * 128;
  int wn = (wave & 3) * 64;
  int laneh = lane & 15;
  int lanev = lane >> 4;
  int aswz = ((lanev ^ ((laneh >> 1) & 3)) << 3);

  int prow = tid >> 2;
  int lslot = (tid & 3) ^ ((tid >> 3) & 3);
  const u16* Asrc = A + (m0 + prow) * Kd + lslot * 8;
  const u16* Bsrc = Bt + (n0 + prow) * Kd + lslot * 8;
  size_t srow128 = (size_t)128 * Kd;

  uint32_t aB[2][2], bB[2][2];
#pragma unroll
  for (int b = 0; b < 2; ++b)
#pragma unroll
    for (int k2 = 0; k2 < 2; ++k2) {
      aB[b][k2] = (uint32_t)(uintptr_t)&As[b][k2][(wm + laneh) * 32 + aswz];
      bB[b][k2] = (uint32_t)(uintptr_t)&Bs[b][k2][(wn + laneh) * 32 + aswz];
    }

  f32x4 acc[8][4] = {};
  s16x8 af[4], bf[4];

  // prologue: 6 regions (12 loads); regions (0,0),(0,1) must land now
  STG_A(0, 0, 0); STG_B(0, 0, 0);
  STG_A(0, 1, 0); STG_B(0, 1, 0);
  STG_A(1, 0, 1); STG_B(1, 0, 1);
  GATE4;
  SBARA;

  int NI = Kd >> 7;
  for (int it = 0; it < NI - 1; ++it) {
    int t = 2 * it;
    QPH(0, 0, 0, STG_A(1, 1, t + 1), NOTAIL);
    QPH(0, 0, 1, STG_B(1, 1, t + 1), TAIL_G2);
    QPH(0, 1, 0, STG_A(0, 0, t + 2), NOTAIL);
    QPH(0, 1, 1, STG_B(0, 0, t + 2), TAIL_G2);
    QPH(1, 0, 0, STG_A(0, 1, t + 2), NOTAIL);
    QPH(1, 0, 1, STG_B(0, 1, t + 2), TAIL_G2);
    QPH(1, 1, 0, STG_A(1, 0, t + 3), NOTAIL);
    QPH(1, 1, 1, STG_B(1, 0, t + 3), TAIL_G2);
  }
  {  // final iteration: only (1,1) still staged; drain
    int t = 2 * (NI - 1);
    QPH(0, 0, 0, STG_A(1, 1, t + 1), NOTAIL);
    QPH(0, 0, 1, STG_B(1, 1, t + 1), TAIL_G2);
    QPH(0, 1, 0, NOSTG, NOTAIL);
    QPH(0, 1, 1, NOSTG, TAIL_G0);
    QPH(1, 0, 0, NOSTG, NOTAIL);
    QPH(1, 0, 1, NOSTG, TAIL_B);
    QPH(1, 1, 0, NOSTG, NOTAIL);
    QPH(1, 1, 1, NOSTG, TAIL_B);  // final barrier before epilogue LDS reuse
  }

  // epilogue: exp -> bf16 store via per-wave LDS bounce + per-row atomic sums
  u16* epw = ((u16*)As) + wave * 1152;  // [16][72] u16
#pragma unroll
  for (int a = 0; a < 8; ++a) {
#pragma unroll
    for (int r = 0; r < 4; ++r)
#pragma unroll
      for (int j = 0; j < 4; ++j)
        epw[(lanev * 4 + r) * 72 + laneh + j * 16] =
            f2bf(__expf(acc[a][j][r] * 0.03125f));
    int rowoff = ((a >> 2) * 64) + ((a & 3) * 16);
#pragma unroll
    for (int p = 0; p < 2; ++p) {
      s16x8 v = *(const s16x8*)&epw[((lane >> 3) + 8 * p) * 72 + (lane & 7) * 8];
      size_t grow = m0 + wm + rowoff + (lane >> 3) + 8 * p;
      *(s16x8*)&C[grow * N + n0 + wn + (lane & 7) * 8] = v;
      float s = 0.f;
#pragma unroll
      for (int j = 0; j < 8; ++j) s += bf2f((u16)v[j]);
      s += __shfl_xor(s, 1, 64);
      s += __shfl_xor(s, 2, 64);
      s += __shfl_xor(s, 4, 64);
      if ((lane & 7) == 0) atomicAdd(&sums[grow], s);
    }
  }
}

// ============== 4-phase 256x128 pipelined GEMM (Q-proj / PV) ================
// EPI 0: C bf16 = acc + bias(aux).   EPI 3: C f32 = xres + acc / sums[row].
// Whole-K-tile staging at even phases; GATE0+barrier at odd phase ends only.

#define PSTG(buf, h, kt) do { \
    const u16* sa_ = Asrc + (size_t)(kt) * 64 + (h) * 32; \
    gload_lds16(sa_, &As[buf][h][wave * 512]); \
    gload_lds16(sa_ + srow128, &As[buf][h][wave * 512 + 4096]); \
    const u16* sb_ = Bsrc + (size_t)(kt) * 64 + (h) * 32; \
    gload_lds16(sb_, &Bs[buf][h][wave * 512]); \
  } while (0)

#define STG_FULL(buf, kt) do { PSTG(buf, 0, kt); PSTG(buf, 1, kt); } while (0)

#define PPH(buf, kk, STAGE, TAIL) do { \
    DSRO(af[0], pA[buf][kk], 0); \
    DSRO(af[1], pA[buf][kk], 1024); \
    DSRO(af[2], pA[buf][kk], 2048); \
    DSRO(af[3], pA[buf][kk], 3072); \
    DSRO(bf[0], pB[buf][kk], 0); \
    DSRO(bf[1], pB[buf][kk], 1024); \
    DSRO(bf[2], pB[buf][kk], 2048); \
    DSRO(bf[3], pB[buf][kk], 3072); \
    STAGE; \
    LGKM0; \
    SCHED0; \
    __builtin_amdgcn_s_setprio(1); \
    _Pragma("unroll") \
    for (int i2 = 0; i2 < 4; ++i2) \
      _Pragma("unroll") \
      for (int j2 = 0; j2 < 4; ++j2) \
        acc[i2][j2] = __builtin_amdgcn_mfma_f32_16x16x32_bf16( \
            af[i2], bf[j2], acc[i2][j2], 0, 0, 0); \
    __builtin_amdgcn_s_setprio(0); \
    SCHED0; \
    TAIL; \
  } while (0)

template <int EPI>
__global__ __launch_bounds__(512, 2) void gemm_pipe(
    const u16* __restrict__ A, const u16* __restrict__ Bt,
    void* __restrict__ Cout, const float* __restrict__ aux,
    const float* __restrict__ xres, int M, int N, int Kd) {
  __shared__ u16 As[2][2][256 * 32];  // 64 KiB
  __shared__ u16 Bs[2][2][128 * 32];  // 32 KiB

  int bid = blockIdx.x;
  int bm = (bid & 7) * 4 + ((bid >> 3) & 3);
  int bn = bid >> 5;
  size_t m0 = (size_t)bm << 8;
  size_t n0 = (size_t)bn << 7;

  int tid = threadIdx.x;
  int lane = tid & 63;
  int wave = tid >> 6;
  int wm = (wave >> 1) * 64;
  int wn = (wave & 1) * 64;
  int laneh = lane & 15;
  int lanev = lane >> 4;
  int aswz = ((lanev ^ ((laneh >> 1) & 3)) << 3);

  int prow = tid >> 2;
  int lslot = (tid & 3) ^ ((tid >> 3) & 3);
  const u16* Asrc = A + (m0 + prow) * Kd + lslot * 8;
  const u16* Bsrc = Bt + (n0 + prow) * Kd + lslot * 8;
  size_t srow128 = (size_t)128 * Kd;

  uint32_t pA[2][2], pB[2][2];
#pragma unroll
  for (int b = 0; b < 2; ++b)
#pragma unroll
    for (int k2 = 0; k2 < 2; ++k2) {
      pA[b][k2] = (uint32_t)(uintptr_t)&As[b][k2][(wm + laneh) * 32 + aswz];
      pB[b][k2] = (uint32_t)(uintptr_t)&Bs[b][k2][(wn + laneh) * 32 + aswz];
    }

  f32x4 acc[4][4] = {};
  s16x8 af[4], bf[4];

  STG_FULL(0, 0);
  GATE0;
  SBARA;

  int NI = Kd >> 7;
  for (int it = 0; it < NI - 1; ++it) {
    int t = 2 * it;
    PPH(0, 0, STG_FULL(1, t + 1), NOTAIL);
    PPH(0, 1, NOSTG, TAIL_G0);
    PPH(1, 0, STG_FULL(0, t + 2), NOTAIL);
    PPH(1, 1, NOSTG, TAIL_G0);
  }
  {
    int t = 2 * (NI - 1);
    PPH(0, 0, STG_FULL(1, t + 1), NOTAIL);
    PPH(0, 1, NOSTG, TAIL_G0);
    PPH(1, 0, NOSTG, NOTAIL);
    PPH(1, 1, NOSTG, NOTAIL);
  }

  int crow = (int)m0 + wm + (lanev << 2);
  int ccol = (int)n0 + wn + laneh;

  if constexpr (EPI == 0) {
    u16* C = (u16*)Cout;
#pragma unroll
    for (int mi = 0; mi < 4; ++mi)
#pragma unroll
      for (int r = 0; r < 4; ++r) {
        size_t row = (size_t)(crow + mi * 16 + r);
#pragma unroll
        for (int ni = 0; ni < 4; ++ni)
          C[row * N + ccol + ni * 16] = f2bf(acc[mi][ni][r] + aux[ccol + ni * 16]);
      }
  } else {
    float* C = (float*)Cout;
#pragma unroll
    for (int mi = 0; mi < 4; ++mi)
#pragma unroll
      for (int r = 0; r < 4; ++r) {
        int row = crow + mi * 16 + r;
        float inv = 1.0f / aux[row];
        size_t rbase = (size_t)row * N + ccol;
#pragma unroll
        for (int ni = 0; ni < 4; ++ni)
          C[rbase + ni * 16] = xres[rbase + ni * 16] + acc[mi][ni][r] * inv;
      }
  }
}

// ---------------- NT GEMM 128^2 (K-proj, V-proj^T) --------------------------
template <int EPI>
__global__ __launch_bounds__(256) void gemm_nt(
    const u16* __restrict__ A, const u16* __restrict__ Bt,
    void* __restrict__ Cout, int M, int N, int K,
    const float* __restrict__ aux1) {
  constexpr int BK = 64;
  __shared__ u16 As[128 * BK];
  __shared__ u16 Bs[128 * BK];

  int nwg = gridDim.x;
  int bid = blockIdx.x;
  int swz = ((nwg & 7) == 0) ? ((bid & 7) * (nwg >> 3) + (bid >> 3)) : bid;
  int nbm = M >> 7;
  int bm = swz % nbm;
  int bn = swz / nbm;

  int tid = threadIdx.x;
  int lane = tid & 63;
  int wave = tid >> 6;
  int wm = (wave >> 1) << 6;
  int wn = (wave & 1) << 6;
  size_t m0 = (size_t)bm << 7;
  size_t n0 = (size_t)bn << 7;

  int srow = tid >> 3;
  int scol = (tid & 7) << 3;

  f32x4 acc[4][4] = {};

  const u16* Ag = A + (m0 + srow) * K + scol;
  const u16* Bg = Bt + (n0 + srow) * K + scol;
  u16* Asw = &As[wave * 512];
  u16* Bsw = &Bs[wave * 512];

  int laneh = lane & 15;
  int lanev = lane >> 4;

  for (int k0 = 0; k0 < K; k0 += BK) {
#pragma unroll
    for (int i = 0; i < 4; ++i) {
      gload_lds16(Ag + (size_t)i * 32 * K + k0, Asw + i * 2048);
      gload_lds16(Bg + (size_t)i * 32 * K + k0, Bsw + i * 2048);
    }
    __syncthreads();
#pragma unroll
    for (int kk = 0; kk < 2; ++kk) {
      s16x8 af[4], bfr[4];
#pragma unroll
      for (int i = 0; i < 4; ++i) {
        af[i]  = *(const s16x8*)&As[(wm + i * 16 + laneh) * BK + kk * 32 + lanev * 8];
        bfr[i] = *(const s16x8*)&Bs[(wn + i * 16 + laneh) * BK + kk * 32 + lanev * 8];
      }
#pragma unroll
      for (int mi = 0; mi < 4; ++mi)
#pragma unroll
        for (int ni = 0; ni < 4; ++ni)
          acc[mi][ni] = __builtin_amdgcn_mfma_f32_16x16x32_bf16(
              af[mi], bfr[ni], acc[mi][ni], 0, 0, 0);
    }
    __syncthreads();
  }

  int crow = (int)m0 + wm + (lanev << 2);
  int ccol = (int)n0 + wn + laneh;

  if constexpr (EPI == 0) {
    u16* C = (u16*)Cout;
#pragma unroll
    for (int mi = 0; mi < 4; ++mi)
#pragma unroll
      for (int r = 0; r < 4; ++r) {
        size_t row = (size_t)(crow + mi * 16 + r);
#pragma unroll
        for (int ni = 0; ni < 4; ++ni)
          C[row * N + ccol + ni * 16] = f2bf(acc[mi][ni][r] + aux1[ccol + ni * 16]);
      }
  } else {
    u16* C = (u16*)Cout;  // [N][M]
#pragma unroll
    for (int ni = 0; ni < 4; ++ni) {
      float b = aux1[ccol + ni * 16];
#pragma unroll
      for (int mi = 0; mi < 4; ++mi) {
        s16x4 v;
#pragma unroll
        for (int r = 0; r < 4; ++r) v[r] = (short)f2bf(acc[mi][ni][r] + b);
        *(s16x4*)&C[(size_t)(ccol + ni * 16) * M + crow + mi * 16] = v;
      }
    }
  }
}

extern "C" void kernel_launch(void* const* d_in, const int* in_sizes, int n_in,
                              void* d_out, int out_size, void* d_ws, size_t ws_size,
                              hipStream_t stream) {
  const float* x  = (const float*)d_in[0];
  const float* mb = (const float*)d_in[1];
  const float* Wq = (const float*)d_in[2];
  const float* bq = (const float*)d_in[3];
  const float* Wk = (const float*)d_in[4];
  const float* bk = (const float*)d_in[5];
  const float* Wv = (const float*)d_in[6];
  const float* bv = (const float*)d_in[7];
  float* out = (float*)d_out;

  const int B = 8192, H = 1024, Mm = 4096;

  char* ws = (char*)d_ws;
  u16* xb  = (u16*)ws; ws += (size_t)B * H * 2;
  u16* mbb = (u16*)ws; ws += (size_t)Mm * H * 2;
  u16* Wqt = (u16*)ws; ws += (size_t)H * H * 2;
  u16* Wkt = (u16*)ws; ws += (size_t)H * H * 2;
  u16* Wvt = (u16*)ws; ws += (size_t)H * H * 2;
  u16* Q   = (u16*)ws; ws += (size_t)B * H * 2;
  u16* Kp  = (u16*)ws; ws += (size_t)Mm * H * 2;
  u16* Vt  = (u16*)ws; ws += (size_t)H * Mm * 2;
  u16* S   = (u16*)ws; ws += (size_t)B * Mm * 2;
  float* sums = (float*)ws;

  hipMemsetAsync(sums, 0, (size_t)B * sizeof(float), stream);

  cast_bf16_kernel<<<2048, 256, 0, stream>>>(x, xb, B * H / 8);
  cast_bf16_kernel<<<1024, 256, 0, stream>>>(mb, mbb, Mm * H / 8);
  tcast_kernel<<<(H / 32) * (H / 32), 256, 0, stream>>>(Wq, Wqt, H, H);
  tcast_kernel<<<(H / 32) * (H / 32), 256, 0, stream>>>(Wk, Wkt, H, H);
  tcast_kernel<<<(H / 32) * (H / 32), 256, 0, stream>>>(Wv, Wvt, H, H);

  gemm_pipe<0><<<(B / 256) * (H / 128), 512, 0, stream>>>(
      xb, Wqt, Q, bq, nullptr, B, H, H);
  gemm_nt<0><<<(Mm / 128) * (H / 128), 256, 0, stream>>>(mbb, Wkt, Kp, Mm, H, H, bk);
  gemm_nt<1><<<(Mm / 128) * (H / 128), 256, 0, stream>>>(mbb, Wvt, Vt, Mm, H, H, bv);

  gemm_qkt_exp<<<(B / 256) * (Mm / 256), 512, 0, stream>>>(Q, Kp, S, sums, B, Mm, H);

  gemm_pipe<3><<<(B / 256) * (H / 128), 512, 0, stream>>>(
      S, Vt, out, sums, x, B, H, Mm);
}